// Round 2
// baseline (913.112 us; speedup 1.0000x reference)
//
#include <hip/hip_runtime.h>

#define EPS 1e-5f

typedef unsigned short u16;
typedef unsigned int u32;
typedef __attribute__((ext_vector_type(8))) u16 u16x8;
typedef __attribute__((ext_vector_type(4))) u16 u16x4;
typedef __attribute__((ext_vector_type(2))) u32 u32x2;
typedef __attribute__((ext_vector_type(8))) __bf16 bf16x8;
typedef __attribute__((ext_vector_type(4))) float f32x4;

__device__ __forceinline__ u16 f2bf(float f) {
  unsigned u = __float_as_uint(f);
  u += 0x7fffu + ((u >> 16) & 1u);  // RNE
  return (u16)(u >> 16);
}
__device__ __forceinline__ float bf2f(u16 h) {
  return __uint_as_float(((unsigned)h) << 16);
}
__device__ __forceinline__ f32x4 mfma16(u16x8 a, u16x8 b, f32x4 c) {
  return __builtin_amdgcn_mfma_f32_16x16x32_bf16(
      __builtin_bit_cast(bf16x8, a), __builtin_bit_cast(bf16x8, b), c, 0, 0, 0);
}

// ---------------- K0: pos[h][n][d] = rel_h[h,d,hh] + rel_w[h,d,ww], n = ww*32+hh
__global__ void k_pos(const float* __restrict__ rel_h, const float* __restrict__ rel_w,
                      float* __restrict__ pos_t) {
  int t = blockIdx.x * 256 + threadIdx.x;  // 8*1024*64 = 524288 exact
  int d = t & 63;
  int n = (t >> 6) & 1023;
  int h = t >> 16;
  int hh = n & 31, ww = n >> 5;
  pos_t[t] = rel_h[(h * 64 + d) * 32 + hh] + rel_w[(h * 64 + d) * 32 + ww];
}

// ---------------- K1: s = W_start @ x + b -> qh/ql (n-major, split bf16)
// and Vw = W_lin @ s (bf16 hi, d-major). grid (16 on, 32 b), 256 thr, ob loop inside.
__global__ __launch_bounds__(256) void k_conv(
    const float* __restrict__ x, const float* __restrict__ Ws, const float* __restrict__ bs,
    const float* __restrict__ Wlin,
    u16* __restrict__ qh, u16* __restrict__ ql, u16* __restrict__ vw) {
  __shared__ u16 wt_h[64 * 72], wt_l[64 * 72], xt_h[64 * 72], xt_l[64 * 72];
  __shared__ u16 cb_h[64 * 72], cb_l[64 * 72];
  __shared__ u16 lw_h[64 * 72], lw_l[64 * 72];
  const int on = blockIdx.x, b = blockIdx.y;
  const int n0 = on * 64;
  const int t = threadIdx.x;
  const int w = t >> 6, lane = t & 63, g = lane >> 4, li = lane & 15;
  f32x4 zz = {0.f, 0.f, 0.f, 0.f};

  {  // stage W_lin split (once)
    int e = t >> 2, ds = (t & 3) * 16;
    const float* src = Wlin + e * 64 + ds;
    u16 hi[16], lo[16];
#pragma unroll
    for (int k = 0; k < 4; ++k) {
      f32x4 f = *(const f32x4*)(src + 4 * k);
#pragma unroll
      for (int j = 0; j < 4; ++j) {
        float v = f[j];
        hi[4 * k + j] = f2bf(v);
        lo[4 * k + j] = f2bf(v - bf2f(hi[4 * k + j]));
      }
    }
    u16x8 p0 = {hi[0], hi[1], hi[2], hi[3], hi[4], hi[5], hi[6], hi[7]};
    u16x8 p1 = {hi[8], hi[9], hi[10], hi[11], hi[12], hi[13], hi[14], hi[15]};
    u16x8 q0 = {lo[0], lo[1], lo[2], lo[3], lo[4], lo[5], lo[6], lo[7]};
    u16x8 q1 = {lo[8], lo[9], lo[10], lo[11], lo[12], lo[13], lo[14], lo[15]};
    *(u16x8*)&lw_h[e * 72 + ds] = p0;
    *(u16x8*)&lw_h[e * 72 + ds + 8] = p1;
    *(u16x8*)&lw_l[e * 72 + ds] = q0;
    *(u16x8*)&lw_l[e * 72 + ds + 8] = q1;
  }

  for (int ob = 0; ob < 8; ++ob) {
    const int o0 = ob * 64;
    const int bh = b * 8 + ob;
    f32x4 acc[4];
#pragma unroll
    for (int i = 0; i < 4; ++i) acc[i] = zz;

    for (int kc = 0; kc < 8; ++kc) {
      const int c0 = kc * 64;
      __syncthreads();
      {  // stage W tile [o][c] split, pitch 72
        int o = t & 63, cc = (t >> 6) * 16;
        const float* src = Ws + (size_t)(o0 + o) * 512 + c0 + cc;
        u16 hi[16], lo[16];
#pragma unroll
        for (int k = 0; k < 4; ++k) {
          f32x4 f = *(const f32x4*)(src + 4 * k);
#pragma unroll
          for (int j = 0; j < 4; ++j) {
            float v = f[j];
            hi[4 * k + j] = f2bf(v);
            lo[4 * k + j] = f2bf(v - bf2f(hi[4 * k + j]));
          }
        }
        u16x8 p0 = {hi[0], hi[1], hi[2], hi[3], hi[4], hi[5], hi[6], hi[7]};
        u16x8 p1 = {hi[8], hi[9], hi[10], hi[11], hi[12], hi[13], hi[14], hi[15]};
        u16x8 q0 = {lo[0], lo[1], lo[2], lo[3], lo[4], lo[5], lo[6], lo[7]};
        u16x8 q1 = {lo[8], lo[9], lo[10], lo[11], lo[12], lo[13], lo[14], lo[15]};
        *(u16x8*)&wt_h[o * 72 + cc] = p0;
        *(u16x8*)&wt_h[o * 72 + cc + 8] = p1;
        *(u16x8*)&wt_l[o * 72 + cc] = q0;
        *(u16x8*)&wt_l[o * 72 + cc + 8] = q1;
      }
      {  // stage x tile transposed -> xt[n][c]
        int c = t & 63, nc = (t >> 6) * 16;
        const float* src = x + ((size_t)b * 512 + c0 + c) * 1024 + n0 + nc;
#pragma unroll
        for (int k = 0; k < 4; ++k) {
          f32x4 f = *(const f32x4*)(src + 4 * k);
#pragma unroll
          for (int j = 0; j < 4; ++j) {
            float v = f[j];
            u16 hv = f2bf(v);
            xt_h[(nc + 4 * k + j) * 72 + c] = hv;
            xt_l[(nc + 4 * k + j) * 72 + c] = f2bf(v - bf2f(hv));
          }
        }
      }
      __syncthreads();
      u16x8 ah[2], al[2];
#pragma unroll
      for (int ks = 0; ks < 2; ++ks) {
        ah[ks] = *(const u16x8*)&wt_h[(16 * w + li) * 72 + g * 8 + 32 * ks];
        al[ks] = *(const u16x8*)&wt_l[(16 * w + li) * 72 + g * 8 + 32 * ks];
      }
#pragma unroll
      for (int ks = 0; ks < 2; ++ks) {
#pragma unroll
        for (int nf = 0; nf < 4; ++nf) {
          u16x8 bh2 = *(const u16x8*)&xt_h[(16 * nf + li) * 72 + g * 8 + 32 * ks];
          u16x8 bl2 = *(const u16x8*)&xt_l[(16 * nf + li) * 72 + g * 8 + 32 * ks];
          acc[nf] = mfma16(ah[ks], bh2, acc[nf]);
          acc[nf] = mfma16(ah[ks], bl2, acc[nf]);
          acc[nf] = mfma16(al[ks], bh2, acc[nf]);
        }
      }
    }
    // epilogue: bias, store qh/ql, fill cb split ([n][d], pitch 72)
    float bias[4];
#pragma unroll
    for (int r = 0; r < 4; ++r) bias[r] = bs[o0 + 16 * w + g * 4 + r];
#pragma unroll
    for (int nf = 0; nf < 4; ++nf) {
      int n = n0 + 16 * nf + li;
      u16 hv[4], lv[4];
#pragma unroll
      for (int r = 0; r < 4; ++r) {
        float v = acc[nf][r] + bias[r];
        hv[r] = f2bf(v);
        lv[r] = f2bf(v - bf2f(hv[r]));
        cb_h[(16 * nf + li) * 72 + 16 * w + 4 * g + r] = hv[r];
        cb_l[(16 * nf + li) * 72 + 16 * w + 4 * g + r] = lv[r];
      }
      u16x4 ph = {hv[0], hv[1], hv[2], hv[3]};
      u16x4 pl = {lv[0], lv[1], lv[2], lv[3]};
      size_t base = ((size_t)bh * 1024 + n) * 64 + 16 * w + g * 4;
      *(u16x4*)(qh + base) = ph;
      *(u16x4*)(ql + base) = pl;
    }
    __syncthreads();
    // Vw tile = W_lin @ s  (split 3-term), wave w -> e rows [16w,16w+16)
    f32x4 acc2[4];
#pragma unroll
    for (int i = 0; i < 4; ++i) acc2[i] = zz;
    u16x8 la_h[2], la_l[2];
#pragma unroll
    for (int ks = 0; ks < 2; ++ks) {
      la_h[ks] = *(const u16x8*)&lw_h[(16 * w + li) * 72 + g * 8 + 32 * ks];
      la_l[ks] = *(const u16x8*)&lw_l[(16 * w + li) * 72 + g * 8 + 32 * ks];
    }
#pragma unroll
    for (int ks = 0; ks < 2; ++ks) {
#pragma unroll
      for (int nf = 0; nf < 4; ++nf) {
        u16x8 qb = *(const u16x8*)&cb_h[(16 * nf + li) * 72 + g * 8 + 32 * ks];
        u16x8 ql2 = *(const u16x8*)&cb_l[(16 * nf + li) * 72 + g * 8 + 32 * ks];
        acc2[nf] = mfma16(la_h[ks], qb, acc2[nf]);
        acc2[nf] = mfma16(la_h[ks], ql2, acc2[nf]);
        acc2[nf] = mfma16(la_l[ks], qb, acc2[nf]);
      }
    }
    __syncthreads();  // all cb reads done; reuse xt_h as bounce
#pragma unroll
    for (int nf = 0; nf < 4; ++nf) {
#pragma unroll
      for (int r = 0; r < 4; ++r)
        xt_h[(16 * w + 4 * g + r) * 72 + 16 * nf + li] = f2bf(acc2[nf][r]);
    }
    __syncthreads();
    {  // coalesced Vw store: [bh][e][n]
      int e = t >> 2, nc = (t & 3) * 16;
      u16x8 v0 = *(const u16x8*)&xt_h[e * 72 + nc];
      u16x8 v1 = *(const u16x8*)&xt_h[e * 72 + nc + 8];
      size_t base = ((size_t)bh * 64 + e) * 1024 + n0 + nc;
      *(u16x8*)(vw + base) = v0;
      *(u16x8*)(vw + base + 8) = v1;
    }
  }
}

// ---------------- K2: flash attention, barrier-free inner loop, per (bh, j-half)
// grid 512 (= bh*2 + half), 512 thr (8 waves), JBLK=128, KBLK=64.
__global__ __launch_bounds__(512, 4) void k_attn(
    const u16* __restrict__ qh, const u16* __restrict__ ql, const u16* __restrict__ vw,
    const float* __restrict__ pos_t, float* __restrict__ pout,
    float* __restrict__ qsum_g, float* __restrict__ sump2_g) {
  __shared__ __align__(16) char smem[49152];  // at_h 16K | at_l 16K | pt 8x2K
  __shared__ float wvar[8];
  char* at_h = smem;
  char* at_l = smem + 16384;
  const int bid = blockIdx.x, bh = bid >> 1, half = bid & 1;
  const int b = bh >> 3, h = bh & 7;
  const int t = threadIdx.x, w = t >> 6, lane = t & 63, g = lane >> 4, li = lane & 15;
  char* ptw = smem + 32768 + w * 2048;
  const u16* qhb = qh + (size_t)bh * 65536;
  const u16* qlb = ql + (size_t)bh * 65536;
  const u16* vwb = vw + (size_t)bh * 65536;
  const float* posb = pos_t + (size_t)h * 65536;
  const float SCALE_INV = 0.088388347648318447f;  // 1/sqrt(512/4)
  f32x4 zz = {0.f, 0.f, 0.f, 0.f};
  float wacc = 0.f;

  if (half == 0) {  // qsum[d] (deterministic tree), only one block per bh
    float* qpart = (float*)(smem + 32768);
    float acc = 0.f;
    for (int i = 0; i < 128; ++i) {
      int n = w + 8 * i;
      acc += bf2f(qhb[n * 64 + lane]) + bf2f(qlb[n * 64 + lane]);
    }
    qpart[w * 64 + lane] = acc;
    __syncthreads();
    if (t < 64) {
      float s = 0.f;
#pragma unroll
      for (int ww2 = 0; ww2 < 8; ++ww2) s += qpart[ww2 * 64 + t];
      qsum_g[bh * 64 + t] = s;
    }
  }

  const int swz = (li & 7) << 4;
  const u16* kh_base = qhb + (size_t)li * 64 + 8 * g;
  const u16* kl_base = qlb + (size_t)li * 64 + 8 * g;
  const u16* vw_base = vwb + (size_t)li * 1024 + 8 * g;

  for (int jtl = 0; jtl < 4; ++jtl) {
    const int jg0 = half * 512 + jtl * 128;
    __syncthreads();
    {  // stage queries a' = (qh+ql)/scale + pos, split hi/lo, XOR-swizzled rows
      int jl = t >> 2, ds = (t & 3) * 16;
      const u16* sh = qhb + (size_t)(jg0 + jl) * 64 + ds;
      const u16* sl = qlb + (size_t)(jg0 + jl) * 64 + ds;
      const float* sp = posb + (size_t)(jg0 + jl) * 64 + ds;
      u16x8 hh0 = *(const u16x8*)sh, hh1 = *(const u16x8*)(sh + 8);
      u16x8 ll0 = *(const u16x8*)sl, ll1 = *(const u16x8*)(sl + 8);
      float PP[16];
      *(f32x4*)&PP[0] = *(const f32x4*)(sp);
      *(f32x4*)&PP[4] = *(const f32x4*)(sp + 4);
      *(f32x4*)&PP[8] = *(const f32x4*)(sp + 8);
      *(f32x4*)&PP[12] = *(const f32x4*)(sp + 12);
      u16 A[16], L[16];
#pragma unroll
      for (int k = 0; k < 16; ++k) {
        u16 hv = (k < 8) ? hh0[k] : hh1[k - 8];
        u16 lv = (k < 8) ? ll0[k] : ll1[k - 8];
        float v = (bf2f(hv) + bf2f(lv)) * SCALE_INV + PP[k];
        A[k] = f2bf(v);
        L[k] = f2bf(v - bf2f(A[k]));
      }
      u16x8 a0 = {A[0], A[1], A[2], A[3], A[4], A[5], A[6], A[7]};
      u16x8 a1 = {A[8], A[9], A[10], A[11], A[12], A[13], A[14], A[15]};
      u16x8 b0 = {L[0], L[1], L[2], L[3], L[4], L[5], L[6], L[7]};
      u16x8 b1 = {L[8], L[9], L[10], L[11], L[12], L[13], L[14], L[15]};
      int sw = (jl & 7) << 4;
      int s0 = (t & 3) * 2;
      *(u16x8*)(at_h + jl * 128 + ((s0 * 16) ^ sw)) = a0;
      *(u16x8*)(at_h + jl * 128 + (((s0 + 1) * 16) ^ sw)) = a1;
      *(u16x8*)(at_l + jl * 128 + ((s0 * 16) ^ sw)) = b0;
      *(u16x8*)(at_l + jl * 128 + (((s0 + 1) * 16) ^ sw)) = b1;
    }
    __syncthreads();
    u16x8 qb_h[2], qb_l[2];
    {
      int jr = 16 * w + li;
      int sw = (jr & 7) << 4;
#pragma unroll
      for (int ks = 0; ks < 2; ++ks) {
        qb_h[ks] = *(const u16x8*)(at_h + jr * 128 + (((4 * ks + g) * 16) ^ sw));
        qb_l[ks] = *(const u16x8*)(at_l + jr * 128 + (((4 * ks + g) * 16) ^ sw));
      }
    }
    float m = -3.0e38f, lsum = 0.f, s2 = 0.f;
    f32x4 O[4];
#pragma unroll
    for (int df = 0; df < 4; ++df) O[df] = zz;

    for (int kc = 0; kc < 16; ++kc) {
      const int k0 = kc * 64;
      f32x4 S[4] = {zz, zz, zz, zz};
#pragma unroll
      for (int ks = 0; ks < 2; ++ks) {
#pragma unroll
        for (int nf = 0; nf < 4; ++nf) {
          u16x8 kh = *(const u16x8*)(kh_base + (size_t)k0 * 64 + nf * 1024 + ks * 32);
          u16x8 kl = *(const u16x8*)(kl_base + (size_t)k0 * 64 + nf * 1024 + ks * 32);
          S[nf] = mfma16(kh, qb_h[ks], S[nf]);
          S[nf] = mfma16(kh, qb_l[ks], S[nf]);
          S[nf] = mfma16(kl, qb_h[ks], S[nf]);
        }
      }
      // online softmax: lane owns row j=li; reduce max over the 4 g-lanes only
      float tm = S[0][0];
#pragma unroll
      for (int nf = 0; nf < 4; ++nf)
#pragma unroll
        for (int r = 0; r < 4; ++r) tm = fmaxf(tm, S[nf][r]);
      tm = fmaxf(tm, __shfl_xor(tm, 16, 64));
      tm = fmaxf(tm, __shfl_xor(tm, 32, 64));
      float mn = fmaxf(m, tm);
      float cr = __expf(m - mn);
      m = mn;
      float ps = 0.f, p2 = 0.f;
#pragma unroll
      for (int nf = 0; nf < 4; ++nf) {
#pragma unroll
        for (int r = 0; r < 4; ++r) {
          float e = __expf(S[nf][r] - m);
          S[nf][r] = e;
          ps += e;
          p2 += e * e;
        }
      }
      lsum = lsum * cr + ps;
      s2 = s2 * cr * cr + p2;
#pragma unroll
      for (int df = 0; df < 4; ++df) O[df] *= cr;
      // pack P (bf16) into per-wave swizzled pt: [j-local=li][k-local]
#pragma unroll
      for (int nf = 0; nf < 4; ++nf) {
        u32 w0 = (u32)f2bf(S[nf][0]) | ((u32)f2bf(S[nf][1]) << 16);
        u32 w1 = (u32)f2bf(S[nf][2]) | ((u32)f2bf(S[nf][3]) << 16);
        int slot = 2 * nf + (g >> 1);
        u32x2 pk = {w0, w1};
        *(u32x2*)(ptw + li * 128 + ((slot * 16) ^ swz) + (g & 1) * 8) = pk;
      }
      // PV: A = Vw frags (global, L1-hot), B = P' from pt
#pragma unroll
      for (int ks = 0; ks < 2; ++ks) {
        u16x8 pb = *(const u16x8*)(ptw + li * 128 + (((4 * ks + g) * 16) ^ swz));
#pragma unroll
        for (int df = 0; df < 4; ++df) {
          u16x8 va = *(const u16x8*)(vw_base + df * 16384 + k0 + ks * 32);
          O[df] = mfma16(va, pb, O[df]);
        }
      }
    }
    // finalize: stats lane-local for row j=li
    lsum += __shfl_xor(lsum, 16, 64);
    lsum += __shfl_xor(lsum, 32, 64);
    s2 += __shfl_xor(s2, 16, 64);
    s2 += __shfl_xor(s2, 32, 64);
    float invl = 1.0f / lsum;
#pragma unroll
    for (int df = 0; df < 4; ++df) O[df] *= invl;
    float s2w = s2 * invl * invl;
    s2w += __shfl_xor(s2w, 1, 64);
    s2w += __shfl_xor(s2w, 2, 64);
    s2w += __shfl_xor(s2w, 4, 64);
    s2w += __shfl_xor(s2w, 8, 64);
    wacc += s2w;  // same on all lanes; strip rows summed once
    __syncthreads();  // everyone done with at/pt -> reuse smem as f32 bounce
    float* bounce = (float*)smem;  // [64 e][132]
#pragma unroll
    for (int df = 0; df < 4; ++df)
#pragma unroll
      for (int r = 0; r < 4; ++r)
        bounce[(df * 16 + g * 4 + r) * 132 + 16 * w + li] = O[df][r];
    __syncthreads();
#pragma unroll
    for (int p = 0; p < 4; ++p) {
      int idx = p * 512 + t;
      int e = idx >> 5, ch = idx & 31;
      f32x4 v = *(const f32x4*)&bounce[e * 132 + ch * 4];
      *(f32x4*)&pout[((size_t)b * 512 + h * 64 + e) * 1024 + jg0 + ch * 4] = v;
    }
  }
  if (lane == 0) wvar[w] = wacc;
  __syncthreads();
  if (t == 0) {
    float s = 0.f;
#pragma unroll
    for (int i = 0; i < 8; ++i) s += wvar[i];
    sump2_g[bid] = s;
  }
}

// ---------------- K3: out = invsig * P_out + (b_lin − invsig*mu*W@qsum)[e] + x  (in-place)
__global__ __launch_bounds__(256) void k_fin(
    float* __restrict__ out, const float* __restrict__ x, const float* __restrict__ Wlin,
    const float* __restrict__ blin, const float* __restrict__ qsum_g,
    const float* __restrict__ sump2_g) {
  const int bh = blockIdx.x, t = threadIdx.x;
  __shared__ float cvec[64], qsl[64];
  if (t < 64) qsl[t] = qsum_g[bh * 64 + t];
  __syncthreads();
  const float MU = 1.0f / 1024.0f;
  float var = (sump2_g[2 * bh] + sump2_g[2 * bh + 1]) * (1.0f / 1048576.0f) - MU * MU;
  float isv = 1.0f / sqrtf(var + EPS);
  if (t < 64) {
    float wq = 0.f;
    for (int d = 0; d < 64; ++d) wq += Wlin[t * 64 + d] * qsl[d];
    cvec[t] = blin[t] - isv * MU * wq;
  }
  __syncthreads();
  const size_t base = (size_t)bh * 65536;
  for (int it = 0; it < 64; ++it) {
    int fl = it * 256 + t;
    size_t off = base + (size_t)fl * 4;
    int e = fl >> 8;
    f32x4 po = *(const f32x4*)(out + off);
    f32x4 xv = *(const f32x4*)(x + off);
    float cv = cvec[e];
    f32x4 res;
#pragma unroll
    for (int k = 0; k < 4; ++k) res[k] = isv * po[k] + cv + xv[k];
    *(f32x4*)(out + off) = res;
  }
}

extern "C" void kernel_launch(void* const* d_in, const int* in_sizes, int n_in,
                              void* d_out, int out_size, void* d_ws, size_t ws_size,
                              hipStream_t stream) {
  const float* x = (const float*)d_in[0];
  const float* Ws = (const float*)d_in[1];
  const float* bs = (const float*)d_in[2];
  const float* rh = (const float*)d_in[3];
  const float* rw = (const float*)d_in[4];
  const float* Wl = (const float*)d_in[5];
  const float* bl = (const float*)d_in[6];
  char* wsb = (char*)d_ws;
  u16* qh = (u16*)wsb;                               // 32 MiB  q hi, n-major [bh][n][d]
  u16* ql = (u16*)(wsb + (size_t)33554432);          // 32 MiB  q lo, n-major
  u16* vw = (u16*)(wsb + (size_t)67108864);          // 32 MiB  Vw=W_lin@q hi, d-major [bh][e][n]
  float* pos_t = (float*)(wsb + (size_t)100663296);  //  2 MiB  pos [h][n][d]
  float* qsg = (float*)(wsb + (size_t)102760448);    // 64 KiB  qsum per (bh,d)
  float* s2g = (float*)(wsb + (size_t)102825984);    //  2 KiB  sum(P~^2) per block (512)
  float* out = (float*)d_out;

  k_pos<<<2048, 256, 0, stream>>>(rh, rw, pos_t);
  k_conv<<<dim3(16, 32), 256, 0, stream>>>(x, Ws, bs, Wl, qh, ql, vw);
  k_attn<<<512, 512, 0, stream>>>(qh, ql, vw, pos_t, out, qsg, s2g);
  k_fin<<<256, 256, 0, stream>>>(out, x, Wl, bl, qsg, s2g);
}

// Round 3
// 462.359 us; speedup vs baseline: 1.9749x; 1.9749x over previous
//
#include <hip/hip_runtime.h>

#define EPS 1e-5f

typedef unsigned short u16;
typedef unsigned int u32;
typedef __attribute__((ext_vector_type(8))) u16 u16x8;
typedef __attribute__((ext_vector_type(4))) u16 u16x4;
typedef __attribute__((ext_vector_type(2))) u32 u32x2;
typedef __attribute__((ext_vector_type(8))) __bf16 bf16x8;
typedef __attribute__((ext_vector_type(4))) float f32x4;

typedef __attribute__((address_space(3))) u32 lds_u32;
typedef __attribute__((address_space(1))) const u32 gbl_u32;

__device__ __forceinline__ u16 f2bf(float f) {
  unsigned u = __float_as_uint(f);
  u += 0x7fffu + ((u >> 16) & 1u);  // RNE
  return (u16)(u >> 16);
}
__device__ __forceinline__ float bf2f(u16 h) {
  return __uint_as_float(((unsigned)h) << 16);
}
__device__ __forceinline__ f32x4 mfma16(u16x8 a, u16x8 b, f32x4 c) {
  return __builtin_amdgcn_mfma_f32_16x16x32_bf16(
      __builtin_bit_cast(bf16x8, a), __builtin_bit_cast(bf16x8, b), c, 0, 0, 0);
}
__device__ __forceinline__ void gl16(const u16* g, u16* l) {
  __builtin_amdgcn_global_load_lds((gbl_u32*)g, (lds_u32*)l, 16, 0, 0);
}

// ---------------- K0: pos[h][n][d] = rel_h[h,d,hh] + rel_w[h,d,ww], n = ww*32+hh
__global__ void k_pos(const float* __restrict__ rel_h, const float* __restrict__ rel_w,
                      float* __restrict__ pos_t) {
  int t = blockIdx.x * 256 + threadIdx.x;  // 524288 exact
  int d = t & 63;
  int n = (t >> 6) & 1023;
  int h = t >> 16;
  int hh = n & 31, ww = n >> 5;
  pos_t[t] = rel_h[(h * 64 + d) * 32 + hh] + rel_w[(h * 64 + d) * 32 + ww];
}

// ---------------- K1: s = W_start @ x + b -> qh/ql (n-major); Vw = W_lin @ s (d-major);
// + deterministic qsum partials. grid (16 on, 32 b), 256 thr.
__global__ __launch_bounds__(256) void k_conv(
    const float* __restrict__ x, const float* __restrict__ Ws, const float* __restrict__ bs,
    const float* __restrict__ Wlin,
    u16* __restrict__ qh, u16* __restrict__ ql, u16* __restrict__ vw,
    float* __restrict__ qpart) {
  __shared__ u16 wt_h[64 * 72], wt_l[64 * 72], xt_h[64 * 72], xt_l[64 * 72];
  __shared__ u16 cb_h[64 * 72], cb_l[64 * 72];
  __shared__ u16 lw_h[64 * 72], lw_l[64 * 72];
  const int on = blockIdx.x, b = blockIdx.y;
  const int n0 = on * 64;
  const int t = threadIdx.x;
  const int w = t >> 6, lane = t & 63, g = lane >> 4, li = lane & 15;
  f32x4 zz = {0.f, 0.f, 0.f, 0.f};

  {  // stage W_lin split (once)
    int e = t >> 2, ds = (t & 3) * 16;
    const float* src = Wlin + e * 64 + ds;
    u16 hi[16], lo[16];
#pragma unroll
    for (int k = 0; k < 4; ++k) {
      f32x4 f = *(const f32x4*)(src + 4 * k);
#pragma unroll
      for (int j = 0; j < 4; ++j) {
        float v = f[j];
        hi[4 * k + j] = f2bf(v);
        lo[4 * k + j] = f2bf(v - bf2f(hi[4 * k + j]));
      }
    }
    u16x8 p0 = {hi[0], hi[1], hi[2], hi[3], hi[4], hi[5], hi[6], hi[7]};
    u16x8 p1 = {hi[8], hi[9], hi[10], hi[11], hi[12], hi[13], hi[14], hi[15]};
    u16x8 q0 = {lo[0], lo[1], lo[2], lo[3], lo[4], lo[5], lo[6], lo[7]};
    u16x8 q1 = {lo[8], lo[9], lo[10], lo[11], lo[12], lo[13], lo[14], lo[15]};
    *(u16x8*)&lw_h[e * 72 + ds] = p0;
    *(u16x8*)&lw_h[e * 72 + ds + 8] = p1;
    *(u16x8*)&lw_l[e * 72 + ds] = q0;
    *(u16x8*)&lw_l[e * 72 + ds + 8] = q1;
  }

  for (int ob = 0; ob < 8; ++ob) {
    const int o0 = ob * 64;
    const int bh = b * 8 + ob;
    f32x4 acc[4];
#pragma unroll
    for (int i = 0; i < 4; ++i) acc[i] = zz;

    for (int kc = 0; kc < 8; ++kc) {
      const int c0 = kc * 64;
      __syncthreads();
      {  // stage W tile [o][c] split, pitch 72
        int o = t & 63, cc = (t >> 6) * 16;
        const float* src = Ws + (size_t)(o0 + o) * 512 + c0 + cc;
        u16 hi[16], lo[16];
#pragma unroll
        for (int k = 0; k < 4; ++k) {
          f32x4 f = *(const f32x4*)(src + 4 * k);
#pragma unroll
          for (int j = 0; j < 4; ++j) {
            float v = f[j];
            hi[4 * k + j] = f2bf(v);
            lo[4 * k + j] = f2bf(v - bf2f(hi[4 * k + j]));
          }
        }
        u16x8 p0 = {hi[0], hi[1], hi[2], hi[3], hi[4], hi[5], hi[6], hi[7]};
        u16x8 p1 = {hi[8], hi[9], hi[10], hi[11], hi[12], hi[13], hi[14], hi[15]};
        u16x8 q0 = {lo[0], lo[1], lo[2], lo[3], lo[4], lo[5], lo[6], lo[7]};
        u16x8 q1 = {lo[8], lo[9], lo[10], lo[11], lo[12], lo[13], lo[14], lo[15]};
        *(u16x8*)&wt_h[o * 72 + cc] = p0;
        *(u16x8*)&wt_h[o * 72 + cc + 8] = p1;
        *(u16x8*)&wt_l[o * 72 + cc] = q0;
        *(u16x8*)&wt_l[o * 72 + cc + 8] = q1;
      }
      {  // stage x tile transposed -> xt[n][c]
        int c = t & 63, nc = (t >> 6) * 16;
        const float* src = x + ((size_t)b * 512 + c0 + c) * 1024 + n0 + nc;
#pragma unroll
        for (int k = 0; k < 4; ++k) {
          f32x4 f = *(const f32x4*)(src + 4 * k);
#pragma unroll
          for (int j = 0; j < 4; ++j) {
            float v = f[j];
            u16 hv = f2bf(v);
            xt_h[(nc + 4 * k + j) * 72 + c] = hv;
            xt_l[(nc + 4 * k + j) * 72 + c] = f2bf(v - bf2f(hv));
          }
        }
      }
      __syncthreads();
      u16x8 ah[2], al[2];
#pragma unroll
      for (int ks = 0; ks < 2; ++ks) {
        ah[ks] = *(const u16x8*)&wt_h[(16 * w + li) * 72 + g * 8 + 32 * ks];
        al[ks] = *(const u16x8*)&wt_l[(16 * w + li) * 72 + g * 8 + 32 * ks];
      }
#pragma unroll
      for (int ks = 0; ks < 2; ++ks) {
#pragma unroll
        for (int nf = 0; nf < 4; ++nf) {
          u16x8 bh2 = *(const u16x8*)&xt_h[(16 * nf + li) * 72 + g * 8 + 32 * ks];
          u16x8 bl2 = *(const u16x8*)&xt_l[(16 * nf + li) * 72 + g * 8 + 32 * ks];
          acc[nf] = mfma16(ah[ks], bh2, acc[nf]);
          acc[nf] = mfma16(ah[ks], bl2, acc[nf]);
          acc[nf] = mfma16(al[ks], bh2, acc[nf]);
        }
      }
    }
    // epilogue: bias, qsum partials, store qh/ql, fill cb split ([n][d], pitch 72)
    float bias[4];
#pragma unroll
    for (int r = 0; r < 4; ++r) bias[r] = bs[o0 + 16 * w + g * 4 + r];
    float vq[4] = {0.f, 0.f, 0.f, 0.f};
#pragma unroll
    for (int nf = 0; nf < 4; ++nf) {
      int n = n0 + 16 * nf + li;
      u16 hv[4], lv[4];
#pragma unroll
      for (int r = 0; r < 4; ++r) {
        float v = acc[nf][r] + bias[r];
        vq[r] += v;
        hv[r] = f2bf(v);
        lv[r] = f2bf(v - bf2f(hv[r]));
        cb_h[(16 * nf + li) * 72 + 16 * w + 4 * g + r] = hv[r];
        cb_l[(16 * nf + li) * 72 + 16 * w + 4 * g + r] = lv[r];
      }
      u16x4 ph = {hv[0], hv[1], hv[2], hv[3]};
      u16x4 pl = {lv[0], lv[1], lv[2], lv[3]};
      size_t base = ((size_t)bh * 1024 + n) * 64 + 16 * w + g * 4;
      *(u16x4*)(qh + base) = ph;
      *(u16x4*)(ql + base) = pl;
    }
#pragma unroll
    for (int r = 0; r < 4; ++r) {  // deterministic qsum partial per (bh, on, d)
      float s = vq[r];
      s += __shfl_xor(s, 1, 64);
      s += __shfl_xor(s, 2, 64);
      s += __shfl_xor(s, 4, 64);
      s += __shfl_xor(s, 8, 64);
      if (li == 0) qpart[((size_t)bh * 16 + on) * 64 + 16 * w + 4 * g + r] = s;
    }
    __syncthreads();
    // Vw tile = W_lin @ s  (split 3-term), wave w -> e rows [16w,16w+16)
    f32x4 acc2[4];
#pragma unroll
    for (int i = 0; i < 4; ++i) acc2[i] = zz;
    u16x8 la_h[2], la_l[2];
#pragma unroll
    for (int ks = 0; ks < 2; ++ks) {
      la_h[ks] = *(const u16x8*)&lw_h[(16 * w + li) * 72 + g * 8 + 32 * ks];
      la_l[ks] = *(const u16x8*)&lw_l[(16 * w + li) * 72 + g * 8 + 32 * ks];
    }
#pragma unroll
    for (int ks = 0; ks < 2; ++ks) {
#pragma unroll
      for (int nf = 0; nf < 4; ++nf) {
        u16x8 qb = *(const u16x8*)&cb_h[(16 * nf + li) * 72 + g * 8 + 32 * ks];
        u16x8 ql2 = *(const u16x8*)&cb_l[(16 * nf + li) * 72 + g * 8 + 32 * ks];
        acc2[nf] = mfma16(la_h[ks], qb, acc2[nf]);
        acc2[nf] = mfma16(la_h[ks], ql2, acc2[nf]);
        acc2[nf] = mfma16(la_l[ks], qb, acc2[nf]);
      }
    }
    __syncthreads();  // all cb reads done; reuse xt_h as bounce
#pragma unroll
    for (int nf = 0; nf < 4; ++nf) {
#pragma unroll
      for (int r = 0; r < 4; ++r)
        xt_h[(16 * w + 4 * g + r) * 72 + 16 * nf + li] = f2bf(acc2[nf][r]);
    }
    __syncthreads();
    {  // coalesced Vw store: [bh][e][n]
      int e = t >> 2, nc = (t & 3) * 16;
      u16x8 v0 = *(const u16x8*)&xt_h[e * 72 + nc];
      u16x8 v1 = *(const u16x8*)&xt_h[e * 72 + nc + 8];
      size_t base = ((size_t)bh * 64 + e) * 1024 + n0 + nc;
      *(u16x8*)(vw + base) = v0;
      *(u16x8*)(vw + base + 8) = v1;
    }
  }
}

// ---------------- K2: flash attention per (bh, quarter): 256 j-rows, 2 sets/wave.
// grid 1024 (bh = bid&255, quarter = bid>>8), 512 thr (8 waves).
// K/Vw tiles (64 rows x 64) double-buffered in LDS via global_load_lds, XOR-swizzled.
__global__ __launch_bounds__(512, 4) void k_attn(
    const u16* __restrict__ qh, const u16* __restrict__ ql, const u16* __restrict__ vw,
    const float* __restrict__ pos_t, float* __restrict__ pout, float* __restrict__ sump2_g) {
  __shared__ __align__(16) u16 kbuf[2][3][4096];  // [buf][{kh,kl,vw}][64*64] 48KB
  __shared__ __align__(16) u16 ptw_all[8][1024];  // per-wave P scratch 16KB
  __shared__ float wvar[8];
  const int bid = blockIdx.x, bh = bid & 255, quarter = bid >> 8;
  const int b = bh >> 3, h = bh & 7;
  const int t = threadIdx.x, w = t >> 6, lane = t & 63, g = lane >> 4, li = lane & 15;
  char* ptw = (char*)&ptw_all[w][0];
  const u16* qhb = qh + (size_t)bh * 65536;
  const u16* qlb = ql + (size_t)bh * 65536;
  const u16* vwb = vw + (size_t)bh * 65536;
  const float* posb = pos_t + (size_t)h * 65536;
  const float SCALE_INV = 0.088388347648318447f;  // 1/sqrt(512/4)
  const int swz = (li & 7) << 4;
  f32x4 zz = {0.f, 0.f, 0.f, 0.f};

  // ---- Q fragments for both sets, straight from global (once per block)
  u16x8 qb_h[2][2], qb_l[2][2];
  const int jr0 = quarter * 256 + 16 * w;
#pragma unroll
  for (int s = 0; s < 2; ++s) {
    int jr = jr0 + s * 128 + li;
#pragma unroll
    for (int ks = 0; ks < 2; ++ks) {
      int dc = 32 * ks + 8 * g;
      u16x8 hh = *(const u16x8*)(qhb + (size_t)jr * 64 + dc);
      u16x8 ll = *(const u16x8*)(qlb + (size_t)jr * 64 + dc);
      const float* sp = posb + (size_t)jr * 64 + dc;
      f32x4 p0 = *(const f32x4*)sp, p1 = *(const f32x4*)(sp + 4);
      u16 A[8], L[8];
#pragma unroll
      for (int k = 0; k < 8; ++k) {
        float pv = (k < 4) ? p0[k] : p1[k - 4];
        float v = (bf2f(hh[k]) + bf2f(ll[k])) * SCALE_INV + pv;
        A[k] = f2bf(v);
        L[k] = f2bf(v - bf2f(A[k]));
      }
      u16x8 av = {A[0], A[1], A[2], A[3], A[4], A[5], A[6], A[7]};
      u16x8 lv = {L[0], L[1], L[2], L[3], L[4], L[5], L[6], L[7]};
      qb_h[s][ks] = av;
      qb_l[s][ks] = lv;
    }
  }

// staging: wave w stages KB-chunk w (rows 8w..8w+7) of each sub-buffer; source
// col-group pre-swizzled so linear LDS dest yields read-side XOR layout.
#define STAGE(bb, k0)                                                         \
  do {                                                                        \
    int r8 = lane >> 3, c8 = (lane & 7) ^ r8;                                 \
    int rq = (k0) + 8 * w + r8;                                               \
    gl16(qhb + (size_t)rq * 64 + 8 * c8, &kbuf[bb][0][w * 512]);              \
    gl16(qlb + (size_t)rq * 64 + 8 * c8, &kbuf[bb][1][w * 512]);              \
    gl16(vwb + (size_t)(8 * w + r8) * 1024 + (k0) + 8 * c8,                   \
         &kbuf[bb][2][w * 512]);                                              \
  } while (0)

  float m0 = -3.0e38f, l0 = 0.f, s20 = 0.f;
  float m1 = -3.0e38f, l1 = 0.f, s21 = 0.f;
  f32x4 O0[4], O1[4];
#pragma unroll
  for (int df = 0; df < 4; ++df) {
    O0[df] = zz;
    O1[df] = zz;
  }

#define SOFTPV(S, mm, ll, ss2, O)                                             \
  do {                                                                        \
    float tm = S[0][0];                                                       \
    _Pragma("unroll") for (int nf = 0; nf < 4; ++nf)                          \
        _Pragma("unroll") for (int r = 0; r < 4; ++r) tm =                    \
        fmaxf(tm, S[nf][r]);                                                  \
    tm = fmaxf(tm, __shfl_xor(tm, 16, 64));                                   \
    tm = fmaxf(tm, __shfl_xor(tm, 32, 64));                                   \
    float mn = fmaxf(mm, tm);                                                 \
    float cr = __expf(mm - mn);                                               \
    mm = mn;                                                                  \
    float ps = 0.f, p2 = 0.f;                                                 \
    _Pragma("unroll") for (int nf = 0; nf < 4; ++nf) {                        \
      _Pragma("unroll") for (int r = 0; r < 4; ++r) {                         \
        float e = __expf(S[nf][r] - mn);                                      \
        S[nf][r] = e;                                                         \
        ps += e;                                                              \
        p2 += e * e;                                                          \
      }                                                                       \
    }                                                                         \
    ll = ll * cr + ps;                                                        \
    ss2 = ss2 * cr * cr + p2;                                                 \
    _Pragma("unroll") for (int df = 0; df < 4; ++df) O[df] *= cr;             \
    _Pragma("unroll") for (int nf = 0; nf < 4; ++nf) {                        \
      u32 w0 = (u32)f2bf(S[nf][0]) | ((u32)f2bf(S[nf][1]) << 16);             \
      u32 w1 = (u32)f2bf(S[nf][2]) | ((u32)f2bf(S[nf][3]) << 16);             \
      int slot = 2 * nf + (g >> 1);                                           \
      u32x2 pk = {w0, w1};                                                    \
      *(u32x2*)(ptw + li * 128 + ((slot * 16) ^ swz) + (g & 1) * 8) = pk;     \
    }                                                                         \
    _Pragma("unroll") for (int ks = 0; ks < 2; ++ks) {                        \
      u16x8 pb = *(const u16x8*)(ptw + li * 128 + (((4 * ks + g) * 16) ^ swz)); \
      _Pragma("unroll") for (int df = 0; df < 4; ++df) {                      \
        u16x8 va = *(const u16x8*)(vb + (16 * df + li) * 128 +                \
                                   ((((4 * ks + g)) * 16) ^ swz));            \
        O[df] = mfma16(va, pb, O[df]);                                        \
      }                                                                       \
    }                                                                         \
  } while (0)

  int cur = 0;
  STAGE(0, 0);
  __syncthreads();
  for (int kc = 0; kc < 16; ++kc) {
    if (kc < 15) {
      int nb = cur ^ 1;
      STAGE(nb, (kc + 1) * 64);
    }
    const char* kb = (const char*)&kbuf[cur][0][0];
    const char* lb = (const char*)&kbuf[cur][1][0];
    const char* vb = (const char*)&kbuf[cur][2][0];
    f32x4 S0[4] = {zz, zz, zz, zz};
    f32x4 S1[4] = {zz, zz, zz, zz};
#pragma unroll
    for (int ks = 0; ks < 2; ++ks) {
#pragma unroll
      for (int nf = 0; nf < 4; ++nf) {
        int off = (16 * nf + li) * 128 + (((4 * ks + g) * 16) ^ swz);
        u16x8 kh = *(const u16x8*)(kb + off);
        u16x8 kl = *(const u16x8*)(lb + off);
        S0[nf] = mfma16(kh, qb_h[0][ks], S0[nf]);
        S0[nf] = mfma16(kl, qb_h[0][ks], S0[nf]);
        S0[nf] = mfma16(kh, qb_l[0][ks], S0[nf]);
        S1[nf] = mfma16(kh, qb_h[1][ks], S1[nf]);
        S1[nf] = mfma16(kl, qb_h[1][ks], S1[nf]);
        S1[nf] = mfma16(kh, qb_l[1][ks], S1[nf]);
      }
    }
    SOFTPV(S0, m0, l0, s20, O0);
    SOFTPV(S1, m1, l1, s21, O1);
    __syncthreads();
    cur ^= 1;
  }

  // ---- finalize stats (lane-local rows), accumulate sum(P~^2)
  float wacc = 0.f;
  l0 += __shfl_xor(l0, 16, 64);
  l0 += __shfl_xor(l0, 32, 64);
  s20 += __shfl_xor(s20, 16, 64);
  s20 += __shfl_xor(s20, 32, 64);
  l1 += __shfl_xor(l1, 16, 64);
  l1 += __shfl_xor(l1, 32, 64);
  s21 += __shfl_xor(s21, 16, 64);
  s21 += __shfl_xor(s21, 32, 64);
  float il0 = 1.0f / l0, il1 = 1.0f / l1;
#pragma unroll
  for (int df = 0; df < 4; ++df) {
    O0[df] *= il0;
    O1[df] *= il1;
  }
  {
    float s2w = s20 * il0 * il0;
    s2w += __shfl_xor(s2w, 1, 64);
    s2w += __shfl_xor(s2w, 2, 64);
    s2w += __shfl_xor(s2w, 4, 64);
    s2w += __shfl_xor(s2w, 8, 64);
    wacc += s2w;
    float s2w1 = s21 * il1 * il1;
    s2w1 += __shfl_xor(s2w1, 1, 64);
    s2w1 += __shfl_xor(s2w1, 2, 64);
    s2w1 += __shfl_xor(s2w1, 4, 64);
    s2w1 += __shfl_xor(s2w1, 8, 64);
    wacc += s2w1;
  }
  if (lane == 0) wvar[w] = wacc;

  // ---- write both sets via f32 LDS bounce (alias kbuf), coalesced stores
  float* bounce = (float*)&kbuf[0][0][0];  // [64 e][132]
#pragma unroll
  for (int s = 0; s < 2; ++s) {
    const int jg0 = quarter * 256 + s * 128;
    __syncthreads();
#pragma unroll
    for (int df = 0; df < 4; ++df)
#pragma unroll
      for (int r = 0; r < 4; ++r)
        bounce[(df * 16 + g * 4 + r) * 132 + 16 * w + li] = s ? O1[df][r] : O0[df][r];
    __syncthreads();
#pragma unroll
    for (int p = 0; p < 4; ++p) {
      int idx = p * 512 + t;
      int e = idx >> 5, ch = idx & 31;
      f32x4 v = *(const f32x4*)&bounce[e * 132 + ch * 4];
      *(f32x4*)&pout[((size_t)b * 512 + h * 64 + e) * 1024 + jg0 + ch * 4] = v;
    }
  }
  __syncthreads();
  if (t == 0) {
    float s = 0.f;
#pragma unroll
    for (int i = 0; i < 8; ++i) s += wvar[i];
    sump2_g[bid] = s;
  }
#undef STAGE
#undef SOFTPV
}

// ---------------- K3: out = isv * P_out + (b_lin - isv*mu*W@qsum)[e] + x  (in-place)
__global__ __launch_bounds__(256) void k_fin(
    float* __restrict__ out, const float* __restrict__ x, const float* __restrict__ Wlin,
    const float* __restrict__ blin, const float* __restrict__ qpart,
    const float* __restrict__ sump2_g) {
  const int bh = blockIdx.x, t = threadIdx.x;
  __shared__ float cvec[64], qsl[64];
  if (t < 64) {
    float s = 0.f;
#pragma unroll
    for (int on = 0; on < 16; ++on) s += qpart[((size_t)bh * 16 + on) * 64 + t];
    qsl[t] = s;
  }
  __syncthreads();
  const float MU = 1.0f / 1024.0f;
  float sp2 = sump2_g[bh] + sump2_g[bh + 256] + sump2_g[bh + 512] + sump2_g[bh + 768];
  float var = sp2 * (1.0f / 1048576.0f) - MU * MU;
  float isv = 1.0f / sqrtf(var + EPS);
  if (t < 64) {
    float wq = 0.f;
    for (int d = 0; d < 64; ++d) wq += Wlin[t * 64 + d] * qsl[d];
    cvec[t] = blin[t] - isv * MU * wq;
  }
  __syncthreads();
  const size_t base = (size_t)bh * 65536;
  for (int it = 0; it < 64; ++it) {
    int fl = it * 256 + t;
    size_t off = base + (size_t)fl * 4;
    int e = fl >> 8;
    f32x4 po = *(const f32x4*)(out + off);
    f32x4 xv = *(const f32x4*)(x + off);
    float cv = cvec[e];
    f32x4 res;
#pragma unroll
    for (int k = 0; k < 4; ++k) res[k] = isv * po[k] + cv + xv[k];
    *(f32x4*)(out + off) = res;
  }
}

extern "C" void kernel_launch(void* const* d_in, const int* in_sizes, int n_in,
                              void* d_out, int out_size, void* d_ws, size_t ws_size,
                              hipStream_t stream) {
  const float* x = (const float*)d_in[0];
  const float* Ws = (const float*)d_in[1];
  const float* bs = (const float*)d_in[2];
  const float* rh = (const float*)d_in[3];
  const float* rw = (const float*)d_in[4];
  const float* Wl = (const float*)d_in[5];
  const float* bl = (const float*)d_in[6];
  char* wsb = (char*)d_ws;
  u16* qh = (u16*)wsb;                               // 32 MiB  q hi, n-major [bh][n][d]
  u16* ql = (u16*)(wsb + (size_t)33554432);          // 32 MiB  q lo, n-major
  u16* vw = (u16*)(wsb + (size_t)67108864);          // 32 MiB  Vw=W_lin@q hi, d-major [bh][e][n]
  float* pos_t = (float*)(wsb + (size_t)100663296);  //  2 MiB  pos [h][n][d]
  float* qpart = (float*)(wsb + (size_t)102760448);  //  1 MiB  qsum partials [bh][16 on][64 d]
  float* s2g = (float*)(wsb + (size_t)103809024);    //  4 KiB  sum(P~^2) per block (1024)
  float* out = (float*)d_out;

  k_pos<<<2048, 256, 0, stream>>>(rh, rw, pos_t);
  k_conv<<<dim3(16, 32), 256, 0, stream>>>(x, Ws, bs, Wl, qh, ql, vw, qpart);
  k_attn<<<1024, 512, 0, stream>>>(qh, ql, vw, pos_t, out, s2g);
  k_fin<<<256, 256, 0, stream>>>(out, x, Wl, bl, qpart, s2g);
}

// Round 5
// 414.418 us; speedup vs baseline: 2.2034x; 1.1157x over previous
//
#include <hip/hip_runtime.h>

#define EPS 1e-5f

typedef unsigned short u16;
typedef unsigned int u32;
typedef __attribute__((ext_vector_type(8))) u16 u16x8;
typedef __attribute__((ext_vector_type(4))) u16 u16x4;
typedef __attribute__((ext_vector_type(2))) u32 u32x2;
typedef __attribute__((ext_vector_type(8))) __bf16 bf16x8;
typedef __attribute__((ext_vector_type(4))) float f32x4;

typedef __attribute__((address_space(3))) u32 lds_u32;
typedef __attribute__((address_space(1))) const u32 gbl_u32;

__device__ __forceinline__ u16 f2bf(float f) {
  unsigned u = __float_as_uint(f);
  u += 0x7fffu + ((u >> 16) & 1u);  // RNE
  return (u16)(u >> 16);
}
__device__ __forceinline__ float bf2f(u16 h) {
  return __uint_as_float(((unsigned)h) << 16);
}
__device__ __forceinline__ f32x4 mfma16(u16x8 a, u16x8 b, f32x4 c) {
  return __builtin_amdgcn_mfma_f32_16x16x32_bf16(
      __builtin_bit_cast(bf16x8, a), __builtin_bit_cast(bf16x8, b), c, 0, 0, 0);
}
__device__ __forceinline__ void gl16(const u16* g, u16* l) {
  __builtin_amdgcn_global_load_lds((gbl_u32*)g, (lds_u32*)l, 16, 0, 0);
}

// ---------------- K0: pos[h][n][d] = rel_h[h,d,hh] + rel_w[h,d,ww], n = ww*32+hh
__global__ void k_pos(const float* __restrict__ rel_h, const float* __restrict__ rel_w,
                      float* __restrict__ pos_t) {
  int t = blockIdx.x * 256 + threadIdx.x;  // 524288 exact
  int d = t & 63;
  int n = (t >> 6) & 1023;
  int h = t >> 16;
  int hh = n & 31, ww = n >> 5;
  pos_t[t] = rel_h[(h * 64 + d) * 32 + hh] + rel_w[(h * 64 + d) * 32 + ww];
}

// ---------------- K1: s = W_start @ x + b -> qh/ql (n-major); Vw = W_lin @ s (d-major);
// + deterministic qsum partials. grid (16 on, 32 b), 256 thr.
__global__ __launch_bounds__(256) void k_conv(
    const float* __restrict__ x, const float* __restrict__ Ws, const float* __restrict__ bs,
    const float* __restrict__ Wlin,
    u16* __restrict__ qh, u16* __restrict__ ql, u16* __restrict__ vw,
    float* __restrict__ qpart) {
  __shared__ u16 wt_h[64 * 72], wt_l[64 * 72], xt_h[64 * 72], xt_l[64 * 72];
  __shared__ u16 cb_h[64 * 72], cb_l[64 * 72];
  __shared__ u16 lw_h[64 * 72], lw_l[64 * 72];
  const int on = blockIdx.x, b = blockIdx.y;
  const int n0 = on * 64;
  const int t = threadIdx.x;
  const int w = t >> 6, lane = t & 63, g = lane >> 4, li = lane & 15;
  f32x4 zz = {0.f, 0.f, 0.f, 0.f};

  {  // stage W_lin split (once) — R3-verbatim
    int e = t >> 2, ds = (t & 3) * 16;
    const float* src = Wlin + e * 64 + ds;
    u16 hi[16], lo[16];
#pragma unroll
    for (int k = 0; k < 4; ++k) {
      f32x4 f = *(const f32x4*)(src + 4 * k);
#pragma unroll
      for (int j = 0; j < 4; ++j) {
        float v = f[j];
        hi[4 * k + j] = f2bf(v);
        lo[4 * k + j] = f2bf(v - bf2f(hi[4 * k + j]));
      }
    }
    u16x8 p0 = {hi[0], hi[1], hi[2], hi[3], hi[4], hi[5], hi[6], hi[7]};
    u16x8 p1 = {hi[8], hi[9], hi[10], hi[11], hi[12], hi[13], hi[14], hi[15]};
    u16x8 q0 = {lo[0], lo[1], lo[2], lo[3], lo[4], lo[5], lo[6], lo[7]};
    u16x8 q1 = {lo[8], lo[9], lo[10], lo[11], lo[12], lo[13], lo[14], lo[15]};
    *(u16x8*)&lw_h[e * 72 + ds] = p0;
    *(u16x8*)&lw_h[e * 72 + ds + 8] = p1;
    *(u16x8*)&lw_l[e * 72 + ds] = q0;
    *(u16x8*)&lw_l[e * 72 + ds + 8] = q1;
  }

  for (int ob = 0; ob < 8; ++ob) {
    const int o0 = ob * 64;
    const int bh = b * 8 + ob;
    f32x4 acc[4];
#pragma unroll
    for (int i = 0; i < 4; ++i) acc[i] = zz;

    for (int kc = 0; kc < 8; ++kc) {
      const int c0 = kc * 64;
      __syncthreads();
      {  // stage W tile [o][c] split, pitch 72 — coalesced map (4 lanes/row)
        int o = t >> 2, cs = (t & 3) * 16;
        const float* src = Ws + (size_t)(o0 + o) * 512 + c0 + cs;
        u16 hi[16], lo[16];
#pragma unroll
        for (int k = 0; k < 4; ++k) {
          f32x4 f = *(const f32x4*)(src + 4 * k);
#pragma unroll
          for (int j = 0; j < 4; ++j) {
            float v = f[j];
            hi[4 * k + j] = f2bf(v);
            lo[4 * k + j] = f2bf(v - bf2f(hi[4 * k + j]));
          }
        }
        u16x8 p0 = {hi[0], hi[1], hi[2], hi[3], hi[4], hi[5], hi[6], hi[7]};
        u16x8 p1 = {hi[8], hi[9], hi[10], hi[11], hi[12], hi[13], hi[14], hi[15]};
        u16x8 q0 = {lo[0], lo[1], lo[2], lo[3], lo[4], lo[5], lo[6], lo[7]};
        u16x8 q1 = {lo[8], lo[9], lo[10], lo[11], lo[12], lo[13], lo[14], lo[15]};
        *(u16x8*)&wt_h[o * 72 + cs] = p0;
        *(u16x8*)&wt_h[o * 72 + cs + 8] = p1;
        *(u16x8*)&wt_l[o * 72 + cs] = q0;
        *(u16x8*)&wt_l[o * 72 + cs + 8] = q1;
      }
      {  // stage x tile transposed -> xt[n][c] — coalesced map (4 lanes/row)
        int c = t >> 2, ns = (t & 3) * 16;
        const float* src = x + ((size_t)b * 512 + c0 + c) * 1024 + n0 + ns;
#pragma unroll
        for (int k = 0; k < 4; ++k) {
          f32x4 f = *(const f32x4*)(src + 4 * k);
#pragma unroll
          for (int j = 0; j < 4; ++j) {
            float v = f[j];
            u16 hv = f2bf(v);
            int n = ns + 4 * k + j;
            xt_h[n * 72 + c] = hv;
            xt_l[n * 72 + c] = f2bf(v - bf2f(hv));
          }
        }
      }
      __syncthreads();
      u16x8 ah[2], al[2];
#pragma unroll
      for (int ks = 0; ks < 2; ++ks) {
        ah[ks] = *(const u16x8*)&wt_h[(16 * w + li) * 72 + g * 8 + 32 * ks];
        al[ks] = *(const u16x8*)&wt_l[(16 * w + li) * 72 + g * 8 + 32 * ks];
      }
#pragma unroll
      for (int ks = 0; ks < 2; ++ks) {
#pragma unroll
        for (int nf = 0; nf < 4; ++nf) {
          u16x8 bh2 = *(const u16x8*)&xt_h[(16 * nf + li) * 72 + g * 8 + 32 * ks];
          u16x8 bl2 = *(const u16x8*)&xt_l[(16 * nf + li) * 72 + g * 8 + 32 * ks];
          acc[nf] = mfma16(ah[ks], bh2, acc[nf]);
          acc[nf] = mfma16(ah[ks], bl2, acc[nf]);
          acc[nf] = mfma16(al[ks], bh2, acc[nf]);
        }
      }
    }
    // epilogue: bias, qsum partials, store qh/ql, fill cb split ([n][d], pitch 72)
    float bias[4];
#pragma unroll
    for (int r = 0; r < 4; ++r) bias[r] = bs[o0 + 16 * w + g * 4 + r];
    float vq[4] = {0.f, 0.f, 0.f, 0.f};
#pragma unroll
    for (int nf = 0; nf < 4; ++nf) {
      int n = n0 + 16 * nf + li;
      u16 hv[4], lv[4];
#pragma unroll
      for (int r = 0; r < 4; ++r) {
        float v = acc[nf][r] + bias[r];
        vq[r] += v;
        hv[r] = f2bf(v);
        lv[r] = f2bf(v - bf2f(hv[r]));
        cb_h[(16 * nf + li) * 72 + 16 * w + 4 * g + r] = hv[r];
        cb_l[(16 * nf + li) * 72 + 16 * w + 4 * g + r] = lv[r];
      }
      u16x4 ph = {hv[0], hv[1], hv[2], hv[3]};
      u16x4 pl = {lv[0], lv[1], lv[2], lv[3]};
      size_t base = ((size_t)bh * 1024 + n) * 64 + 16 * w + g * 4;
      *(u16x4*)(qh + base) = ph;
      *(u16x4*)(ql + base) = pl;
    }
#pragma unroll
    for (int r = 0; r < 4; ++r) {  // deterministic qsum partial per (bh, on, d)
      float s = vq[r];
      s += __shfl_xor(s, 1, 64);
      s += __shfl_xor(s, 2, 64);
      s += __shfl_xor(s, 4, 64);
      s += __shfl_xor(s, 8, 64);
      if (li == 0) qpart[((size_t)bh * 16 + on) * 64 + 16 * w + 4 * g + r] = s;
    }
    __syncthreads();
    // Vw tile = W_lin @ s  (split 3-term), wave w -> e rows [16w,16w+16)
    f32x4 acc2[4];
#pragma unroll
    for (int i = 0; i < 4; ++i) acc2[i] = zz;
    u16x8 la_h[2], la_l[2];
#pragma unroll
    for (int ks = 0; ks < 2; ++ks) {
      la_h[ks] = *(const u16x8*)&lw_h[(16 * w + li) * 72 + g * 8 + 32 * ks];
      la_l[ks] = *(const u16x8*)&lw_l[(16 * w + li) * 72 + g * 8 + 32 * ks];
    }
#pragma unroll
    for (int ks = 0; ks < 2; ++ks) {
#pragma unroll
      for (int nf = 0; nf < 4; ++nf) {
        u16x8 qb = *(const u16x8*)&cb_h[(16 * nf + li) * 72 + g * 8 + 32 * ks];
        u16x8 ql2 = *(const u16x8*)&cb_l[(16 * nf + li) * 72 + g * 8 + 32 * ks];
        acc2[nf] = mfma16(la_h[ks], qb, acc2[nf]);
        acc2[nf] = mfma16(la_h[ks], ql2, acc2[nf]);
        acc2[nf] = mfma16(la_l[ks], qb, acc2[nf]);
      }
    }
    __syncthreads();  // all cb reads done; reuse xt_h as bounce
#pragma unroll
    for (int nf = 0; nf < 4; ++nf) {
#pragma unroll
      for (int r = 0; r < 4; ++r)
        xt_h[(16 * w + 4 * g + r) * 72 + 16 * nf + li] = f2bf(acc2[nf][r]);
    }
    __syncthreads();
    {  // coalesced Vw store: [bh][e][n]
      int e = t >> 2, nc = (t & 3) * 16;
      u16x8 v0 = *(const u16x8*)&xt_h[e * 72 + nc];
      u16x8 v1 = *(const u16x8*)&xt_h[e * 72 + nc + 8];
      size_t base = ((size_t)bh * 64 + e) * 1024 + n0 + nc;
      *(u16x8*)(vw + base) = v0;
      *(u16x8*)(vw + base + 8) = v1;
    }
  }
}

// ---------------- K2: flash attention per (bh, quarter): 256 j-rows, 2 sets/wave.
// log2-domain energies, always-rescale online softmax (R3 control flow), merged PV.
__global__ __launch_bounds__(512, 4) void k_attn(
    const u16* __restrict__ qh, const u16* __restrict__ ql, const u16* __restrict__ vw,
    const float* __restrict__ pos_t, float* __restrict__ pout, float* __restrict__ sump2_g) {
  __shared__ __align__(16) u16 kbuf[2][3][4096];  // [buf][{kh,kl,vw}][64*64] 48KB
  __shared__ __align__(16) u16 ptw_all[8][1024];  // per-wave P scratch 16KB
  __shared__ float wvar[8];
  const int bid = blockIdx.x, bh = bid & 255, quarter = bid >> 8;
  const int b = bh >> 3, h = bh & 7;
  const int t = threadIdx.x, w = t >> 6, lane = t & 63, g = lane >> 4, li = lane & 15;
  char* ptw = (char*)&ptw_all[w][0];
  const u16* qhb = qh + (size_t)bh * 65536;
  const u16* qlb = ql + (size_t)bh * 65536;
  const u16* vwb = vw + (size_t)bh * 65536;
  const float* posb = pos_t + (size_t)h * 65536;
  const float SIL = 0.088388347648318447f * 1.4426950408889634f;  // (1/sqrt(128))*log2e
  const float L2E = 1.4426950408889634f;
  const int swz = (li & 7) << 4;
  f32x4 zz = {0.f, 0.f, 0.f, 0.f};

  // ---- Q fragments for both sets (log2-scaled), straight from global (R3 structure)
  u16x8 qb_h[2][2], qb_l[2][2];
  const int jr0 = quarter * 256 + 16 * w;
#pragma unroll
  for (int s = 0; s < 2; ++s) {
    int jr = jr0 + s * 128 + li;
#pragma unroll
    for (int ks = 0; ks < 2; ++ks) {
      int dc = 32 * ks + 8 * g;
      u16x8 hh = *(const u16x8*)(qhb + (size_t)jr * 64 + dc);
      u16x8 ll = *(const u16x8*)(qlb + (size_t)jr * 64 + dc);
      const float* sp = posb + (size_t)jr * 64 + dc;
      f32x4 p0 = *(const f32x4*)sp, p1 = *(const f32x4*)(sp + 4);
      u16 A[8], L[8];
#pragma unroll
      for (int k = 0; k < 8; ++k) {
        float pv = (k < 4) ? p0[k] : p1[k - 4];
        float v = (bf2f(hh[k]) + bf2f(ll[k])) * SIL + pv * L2E;
        A[k] = f2bf(v);
        L[k] = f2bf(v - bf2f(A[k]));
      }
      u16x8 av = {A[0], A[1], A[2], A[3], A[4], A[5], A[6], A[7]};
      u16x8 lv = {L[0], L[1], L[2], L[3], L[4], L[5], L[6], L[7]};
      qb_h[s][ks] = av;
      qb_l[s][ks] = lv;
    }
  }

#define STAGE(bb, k0)                                                         \
  do {                                                                        \
    int r8 = lane >> 3, c8 = (lane & 7) ^ r8;                                 \
    int rq = (k0) + 8 * w + r8;                                               \
    gl16(qhb + (size_t)rq * 64 + 8 * c8, &kbuf[bb][0][w * 512]);              \
    gl16(qlb + (size_t)rq * 64 + 8 * c8, &kbuf[bb][1][w * 512]);              \
    gl16(vwb + (size_t)(8 * w + r8) * 1024 + (k0) + 8 * c8,                   \
         &kbuf[bb][2][w * 512]);                                              \
  } while (0)

  float m0 = -3.0e38f, l0 = 0.f, s20 = 0.f;
  float m1 = -3.0e38f, l1 = 0.f, s21 = 0.f;
  f32x4 O0[4], O1[4];
#pragma unroll
  for (int df = 0; df < 4; ++df) {
    O0[df] = zz;
    O1[df] = zz;
  }

  // R3 control flow: ALWAYS-rescale online softmax (exp2 domain); P-pack f2bf.
#define SOFT(S, mm, ll, ss2, O)                                               \
  do {                                                                        \
    float tm = S[0][0];                                                       \
    _Pragma("unroll") for (int nf = 0; nf < 4; ++nf)                          \
        _Pragma("unroll") for (int r = 0; r < 4; ++r) tm =                    \
        fmaxf(tm, S[nf][r]);                                                  \
    tm = fmaxf(tm, __shfl_xor(tm, 16, 64));                                   \
    tm = fmaxf(tm, __shfl_xor(tm, 32, 64));                                   \
    float mn = fmaxf(mm, tm);                                                 \
    float cr = __builtin_amdgcn_exp2f(mm - mn);                               \
    mm = mn;                                                                  \
    float ps = 0.f, p2 = 0.f;                                                 \
    _Pragma("unroll") for (int nf = 0; nf < 4; ++nf) {                        \
      _Pragma("unroll") for (int r = 0; r < 4; ++r) {                         \
        float e = __builtin_amdgcn_exp2f(S[nf][r] - mn);                      \
        S[nf][r] = e;                                                         \
        ps += e;                                                              \
        p2 = fmaf(e, e, p2);                                                  \
      }                                                                       \
    }                                                                         \
    ll = ll * cr + ps;                                                        \
    ss2 = ss2 * cr * cr + p2;                                                 \
    _Pragma("unroll") for (int df = 0; df < 4; ++df) O[df] *= cr;             \
    _Pragma("unroll") for (int nf = 0; nf < 4; ++nf) {                        \
      u32 w0 = (u32)f2bf(S[nf][0]) | ((u32)f2bf(S[nf][1]) << 16);             \
      u32 w1 = (u32)f2bf(S[nf][2]) | ((u32)f2bf(S[nf][3]) << 16);             \
      int slot = 2 * nf + (g >> 1);                                           \
      u32x2 pk = {w0, w1};                                                    \
      *(u32x2*)(ptw + li * 128 + ((slot * 16) ^ swz) + (g & 1) * 8) = pk;     \
    }                                                                         \
  } while (0)

  int cur = 0;
  STAGE(0, 0);
  __syncthreads();
  for (int kc = 0; kc < 16; ++kc) {
    if (kc < 15) STAGE(cur ^ 1, (kc + 1) * 64);
    const char* kb = (const char*)&kbuf[cur][0][0];
    const char* lb = (const char*)&kbuf[cur][1][0];
    const char* vb = (const char*)&kbuf[cur][2][0];
    f32x4 S0[4] = {zz, zz, zz, zz};
    f32x4 S1[4] = {zz, zz, zz, zz};
    __builtin_amdgcn_s_setprio(1);
#pragma unroll
    for (int ks = 0; ks < 2; ++ks) {
#pragma unroll
      for (int nf = 0; nf < 4; ++nf) {
        int off = (16 * nf + li) * 128 + (((4 * ks + g) * 16) ^ swz);
        u16x8 kh = *(const u16x8*)(kb + off);
        u16x8 kl = *(const u16x8*)(lb + off);
        S0[nf] = mfma16(kh, qb_h[0][ks], S0[nf]);
        S0[nf] = mfma16(kl, qb_h[0][ks], S0[nf]);
        S0[nf] = mfma16(kh, qb_l[0][ks], S0[nf]);
        S1[nf] = mfma16(kh, qb_h[1][ks], S1[nf]);
        S1[nf] = mfma16(kl, qb_h[1][ks], S1[nf]);
        S1[nf] = mfma16(kh, qb_l[1][ks], S1[nf]);
      }
    }
    __builtin_amdgcn_s_setprio(0);
    SOFT(S0, m0, l0, s20, O0);
    u16x8 pb0[2];
    pb0[0] = *(const u16x8*)(ptw + li * 128 + ((g * 16) ^ swz));
    pb0[1] = *(const u16x8*)(ptw + li * 128 + (((4 + g) * 16) ^ swz));
    SOFT(S1, m1, l1, s21, O1);
    u16x8 pb1[2];
    pb1[0] = *(const u16x8*)(ptw + li * 128 + ((g * 16) ^ swz));
    pb1[1] = *(const u16x8*)(ptw + li * 128 + (((4 + g) * 16) ^ swz));
    __builtin_amdgcn_s_setprio(1);
#pragma unroll
    for (int ks = 0; ks < 2; ++ks) {
#pragma unroll
      for (int df = 0; df < 4; ++df) {
        u16x8 va = *(const u16x8*)(vb + (16 * df + li) * 128 + (((4 * ks + g) * 16) ^ swz));
        O0[df] = mfma16(va, pb0[ks], O0[df]);
        O1[df] = mfma16(va, pb1[ks], O1[df]);
      }
    }
    __builtin_amdgcn_s_setprio(0);
    __syncthreads();
    cur ^= 1;
  }

  // ---- finalize stats (lane-local rows), accumulate sum(P~^2)
  float wacc = 0.f;
  l0 += __shfl_xor(l0, 16, 64);
  l0 += __shfl_xor(l0, 32, 64);
  s20 += __shfl_xor(s20, 16, 64);
  s20 += __shfl_xor(s20, 32, 64);
  l1 += __shfl_xor(l1, 16, 64);
  l1 += __shfl_xor(l1, 32, 64);
  s21 += __shfl_xor(s21, 16, 64);
  s21 += __shfl_xor(s21, 32, 64);
  float il0 = 1.0f / l0, il1 = 1.0f / l1;
#pragma unroll
  for (int df = 0; df < 4; ++df) {
    O0[df] *= il0;
    O1[df] *= il1;
  }
  {
    float s2w = s20 * il0 * il0;
    s2w += __shfl_xor(s2w, 1, 64);
    s2w += __shfl_xor(s2w, 2, 64);
    s2w += __shfl_xor(s2w, 4, 64);
    s2w += __shfl_xor(s2w, 8, 64);
    wacc += s2w;
    float s2w1 = s21 * il1 * il1;
    s2w1 += __shfl_xor(s2w1, 1, 64);
    s2w1 += __shfl_xor(s2w1, 2, 64);
    s2w1 += __shfl_xor(s2w1, 4, 64);
    s2w1 += __shfl_xor(s2w1, 8, 64);
    wacc += s2w1;
  }
  if (lane == 0) wvar[w] = wacc;

  // ---- write both sets via f32 LDS bounce (alias kbuf), coalesced stores
  float* bounce = (float*)&kbuf[0][0][0];  // [64 e][132]
#pragma unroll
  for (int s = 0; s < 2; ++s) {
    const int jg0 = quarter * 256 + s * 128;
    __syncthreads();
#pragma unroll
    for (int df = 0; df < 4; ++df)
#pragma unroll
      for (int r = 0; r < 4; ++r)
        bounce[(df * 16 + g * 4 + r) * 132 + 16 * w + li] = s ? O1[df][r] : O0[df][r];
    __syncthreads();
#pragma unroll
    for (int p = 0; p < 4; ++p) {
      int idx = p * 512 + t;
      int e = idx >> 5, ch = idx & 31;
      f32x4 v = *(const f32x4*)&bounce[e * 132 + ch * 4];
      *(f32x4*)&pout[((size_t)b * 512 + h * 64 + e) * 1024 + jg0 + ch * 4] = v;
    }
  }
  __syncthreads();
  if (t == 0) {
    float s = 0.f;
#pragma unroll
    for (int i = 0; i < 8; ++i) s += wvar[i];
    sump2_g[bid] = s;
  }
#undef STAGE
#undef SOFT
}

// ---------------- K3a: per-bh constants: cvec[e] = blin - isv*mu*(W@qsum), isv
__global__ __launch_bounds__(64) void k_cvec(
    const float* __restrict__ qpart, const float* __restrict__ sump2_g,
    const float* __restrict__ Wlin, const float* __restrict__ blin,
    float* __restrict__ cvec_g, float* __restrict__ isv_g) {
  const int bh = blockIdx.x, t = threadIdx.x;
  __shared__ float qs[64];
  float s = 0.f;
#pragma unroll
  for (int on = 0; on < 16; ++on) s += qpart[(size_t)bh * 1024 + on * 64 + t];
  qs[t] = s;
  __syncthreads();
  const float MU = 1.0f / 1024.0f;
  float sp2 = sump2_g[bh] + sump2_g[bh + 256] + sump2_g[bh + 512] + sump2_g[bh + 768];
  float var = sp2 * (1.0f / 1048576.0f) - MU * MU;
  float isv = 1.0f / sqrtf(var + EPS);
  float wq = 0.f;
  for (int d = 0; d < 64; ++d) wq += Wlin[t * 64 + d] * qs[d];
  cvec_g[bh * 64 + t] = blin[t] - isv * MU * wq;
  if (t == 0) isv_g[bh] = isv;
}

// ---------------- K3b: out = isv * P_out + cvec[e] + x  (in-place, pure stream)
__global__ __launch_bounds__(256) void k_fin(
    float* __restrict__ out, const float* __restrict__ x,
    const float* __restrict__ cvec_g, const float* __restrict__ isv_g) {
  const int bid = blockIdx.x, t = threadIdx.x;
  const int bh = bid >> 3, part = bid & 7;
  const float isv = isv_g[bh];
  const size_t base = (size_t)bh * 65536 + part * 8192;
#pragma unroll
  for (int it = 0; it < 8; ++it) {
    size_t off = base + it * 1024 + t * 4;
    float cv = cvec_g[bh * 64 + part * 8 + it];
    f32x4 po = *(const f32x4*)(out + off);
    f32x4 xv = *(const f32x4*)(x + off);
    f32x4 res;
#pragma unroll
    for (int k = 0; k < 4; ++k) res[k] = isv * po[k] + cv + xv[k];
    *(f32x4*)(out + off) = res;
  }
}

extern "C" void kernel_launch(void* const* d_in, const int* in_sizes, int n_in,
                              void* d_out, int out_size, void* d_ws, size_t ws_size,
                              hipStream_t stream) {
  const float* x = (const float*)d_in[0];
  const float* Ws = (const float*)d_in[1];
  const float* bs = (const float*)d_in[2];
  const float* rh = (const float*)d_in[3];
  const float* rw = (const float*)d_in[4];
  const float* Wl = (const float*)d_in[5];
  const float* bl = (const float*)d_in[6];
  char* wsb = (char*)d_ws;
  u16* qh = (u16*)wsb;                               // 32 MiB  q hi, n-major [bh][n][d]
  u16* ql = (u16*)(wsb + (size_t)33554432);          // 32 MiB  q lo, n-major
  u16* vw = (u16*)(wsb + (size_t)67108864);          // 32 MiB  Vw=W_lin@q hi, d-major [bh][e][n]
  float* pos_t = (float*)(wsb + (size_t)100663296);  //  2 MiB  pos [h][n][d]
  float* qpart = (float*)(wsb + (size_t)102760448);  //  1 MiB  qsum partials [bh][16 on][64 d]
  float* s2g = (float*)(wsb + (size_t)103809024);    //  4 KiB  sum(P~^2) per block (1024)
  float* cvec = (float*)(wsb + (size_t)103813120);   // 64 KiB  cvec [bh][64]
  float* isvg = (float*)(wsb + (size_t)103878656);   //  1 KiB  isv per bh
  float* out = (float*)d_out;

  k_pos<<<2048, 256, 0, stream>>>(rh, rw, pos_t);
  k_conv<<<dim3(16, 32), 256, 0, stream>>>(x, Ws, bs, Wl, qh, ql, vw, qpart);
  k_attn<<<1024, 512, 0, stream>>>(qh, ql, vw, pos_t, out, s2g);
  k_cvec<<<256, 64, 0, stream>>>(qpart, s2g, Wl, bl, cvec, isvg);
  k_fin<<<2048, 256, 0, stream>>>(out, x, cvec, isvg);
}

// Round 7
// 362.976 us; speedup vs baseline: 2.5156x; 1.1417x over previous
//
#include <hip/hip_runtime.h>

#define EPS 1e-5f

typedef unsigned short u16;
typedef unsigned int u32;
typedef __attribute__((ext_vector_type(8))) u16 u16x8;
typedef __attribute__((ext_vector_type(4))) u16 u16x4;
typedef __attribute__((ext_vector_type(2))) u32 u32x2;
typedef __attribute__((ext_vector_type(4))) u32 u32x4;
typedef __attribute__((ext_vector_type(8))) __bf16 bf16x8;
typedef __attribute__((ext_vector_type(2))) __bf16 bf16x2;
typedef __attribute__((ext_vector_type(4))) float f32x4;
typedef __attribute__((ext_vector_type(2))) float f32x2;

typedef __attribute__((address_space(3))) u32 lds_u32;
typedef __attribute__((address_space(1))) const u32 gbl_u32;

__device__ __forceinline__ float bf2f(u16 h) {
  return __uint_as_float(((unsigned)h) << 16);
}
// Packed f32x2 -> bf16x2 via compiler (element 0 -> low 16 bits, guaranteed; RNE).
__device__ __forceinline__ u32 pk2bf(float a, float b) {
  f32x2 v = {a, b};
  return __builtin_bit_cast(u32, __builtin_convertvector(v, bf16x2));
}
// Single f32 -> bf16 via compiler (RNE).
__device__ __forceinline__ u16 b2u(float f) {
  return __builtin_bit_cast(u16, (__bf16)f);
}
__device__ __forceinline__ float ubf(u32 u) { return __uint_as_float(u); }
__device__ __forceinline__ f32x4 mfma16(u16x8 a, u16x8 b, f32x4 c) {
  return __builtin_amdgcn_mfma_f32_16x16x32_bf16(
      __builtin_bit_cast(bf16x8, a), __builtin_bit_cast(bf16x8, b), c, 0, 0, 0);
}
__device__ __forceinline__ void gl16(const u16* g, u16* l) {
  __builtin_amdgcn_global_load_lds((gbl_u32*)g, (lds_u32*)l, 16, 0, 0);
}

// ---------------- K0: pos[h][n][d] = rel_h[h,d,hh] + rel_w[h,d,ww], n = ww*32+hh
__global__ void k_pos(const float* __restrict__ rel_h, const float* __restrict__ rel_w,
                      float* __restrict__ pos_t) {
  int t = blockIdx.x * 256 + threadIdx.x;  // 524288 exact
  int d = t & 63;
  int n = (t >> 6) & 1023;
  int h = t >> 16;
  int hh = n & 31, ww = n >> 5;
  pos_t[t] = rel_h[(h * 64 + d) * 32 + hh] + rel_w[(h * 64 + d) * 32 + ww];
}

// ---------------- K1: s = W_start @ x + b -> qh/ql (n-major); Vw = W_lin @ s (d-major);
// + deterministic qsum partials. grid (16 on, 32 b), 256 thr.
__global__ __launch_bounds__(256) void k_conv(
    const float* __restrict__ x, const float* __restrict__ Ws, const float* __restrict__ bs,
    const float* __restrict__ Wlin,
    u16* __restrict__ qh, u16* __restrict__ ql, u16* __restrict__ vw,
    float* __restrict__ qpart) {
  __shared__ u16 wt_h[64 * 72], wt_l[64 * 72], xt_h[64 * 72], xt_l[64 * 72];
  __shared__ u16 cb_h[64 * 72], cb_l[64 * 72];
  __shared__ u16 lw_h[64 * 72], lw_l[64 * 72];
  const int on = blockIdx.x, b = blockIdx.y;
  const int n0 = on * 64;
  const int t = threadIdx.x;
  const int w = t >> 6, lane = t & 63, g = lane >> 4, li = lane & 15;
  f32x4 zz = {0.f, 0.f, 0.f, 0.f};

  {  // stage W_lin split (once) — packed convert
    int e = t >> 2, ds = (t & 3) * 16;
    const float* src = Wlin + e * 64 + ds;
    float arr[16];
#pragma unroll
    for (int k = 0; k < 4; ++k) *(f32x4*)&arr[4 * k] = *(const f32x4*)(src + 4 * k);
#pragma unroll
    for (int p = 0; p < 8; ++p) {
      float a = arr[2 * p], c = arr[2 * p + 1];
      u32 hw = pk2bf(a, c);
      u32 lw = pk2bf(a - ubf(hw << 16), c - ubf(hw & 0xffff0000u));
      *(u32*)&lw_h[e * 72 + ds + 2 * p] = hw;
      *(u32*)&lw_l[e * 72 + ds + 2 * p] = lw;
    }
  }

  for (int ob = 0; ob < 8; ++ob) {
    const int o0 = ob * 64;
    const int bh = b * 8 + ob;
    f32x4 acc[4];
#pragma unroll
    for (int i = 0; i < 4; ++i) acc[i] = zz;

    for (int kc = 0; kc < 8; ++kc) {
      const int c0 = kc * 64;
      __syncthreads();
      {  // stage W tile [o][c] split, pitch 72 — coalesced + packed convert
        int o = t >> 2, cs = (t & 3) * 16;
        const float* src = Ws + (size_t)(o0 + o) * 512 + c0 + cs;
        float arr[16];
#pragma unroll
        for (int k = 0; k < 4; ++k) *(f32x4*)&arr[4 * k] = *(const f32x4*)(src + 4 * k);
        u16* dh = &wt_h[o * 72 + cs];
        u16* dl = &wt_l[o * 72 + cs];
#pragma unroll
        for (int p = 0; p < 8; ++p) {
          float a = arr[2 * p], c = arr[2 * p + 1];
          u32 hw = pk2bf(a, c);
          u32 lw = pk2bf(a - ubf(hw << 16), c - ubf(hw & 0xffff0000u));
          *(u32*)(dh + 2 * p) = hw;
          *(u32*)(dl + 2 * p) = lw;
        }
      }
      {  // stage x tile transposed -> xt[n][c] — coalesced + packed convert
        int c = t >> 2, ns = (t & 3) * 16;
        const float* src = x + ((size_t)b * 512 + c0 + c) * 1024 + n0 + ns;
        float arr[16];
#pragma unroll
        for (int k = 0; k < 4; ++k) *(f32x4*)&arr[4 * k] = *(const f32x4*)(src + 4 * k);
#pragma unroll
        for (int p = 0; p < 8; ++p) {
          float a = arr[2 * p], cc = arr[2 * p + 1];
          u32 hw = pk2bf(a, cc);
          u32 lw = pk2bf(a - ubf(hw << 16), cc - ubf(hw & 0xffff0000u));
          int n = ns + 2 * p;
          xt_h[n * 72 + c] = (u16)hw;
          xt_h[(n + 1) * 72 + c] = (u16)(hw >> 16);
          xt_l[n * 72 + c] = (u16)lw;
          xt_l[(n + 1) * 72 + c] = (u16)(lw >> 16);
        }
      }
      __syncthreads();
      u16x8 ah[2], al[2];
#pragma unroll
      for (int ks = 0; ks < 2; ++ks) {
        ah[ks] = *(const u16x8*)&wt_h[(16 * w + li) * 72 + g * 8 + 32 * ks];
        al[ks] = *(const u16x8*)&wt_l[(16 * w + li) * 72 + g * 8 + 32 * ks];
      }
#pragma unroll
      for (int ks = 0; ks < 2; ++ks) {
#pragma unroll
        for (int nf = 0; nf < 4; ++nf) {
          u16x8 bh2 = *(const u16x8*)&xt_h[(16 * nf + li) * 72 + g * 8 + 32 * ks];
          u16x8 bl2 = *(const u16x8*)&xt_l[(16 * nf + li) * 72 + g * 8 + 32 * ks];
          acc[nf] = mfma16(ah[ks], bh2, acc[nf]);
          acc[nf] = mfma16(ah[ks], bl2, acc[nf]);
          acc[nf] = mfma16(al[ks], bh2, acc[nf]);
        }
      }
    }
    // epilogue: bias, qsum partials, store qh/ql (dwordx2), fill cb split ([n][d])
    float bias[4];
#pragma unroll
    for (int r = 0; r < 4; ++r) bias[r] = bs[o0 + 16 * w + g * 4 + r];
    float vq[4] = {0.f, 0.f, 0.f, 0.f};
#pragma unroll
    for (int nf = 0; nf < 4; ++nf) {
      float v0 = acc[nf][0] + bias[0], v1 = acc[nf][1] + bias[1];
      float v2 = acc[nf][2] + bias[2], v3 = acc[nf][3] + bias[3];
      vq[0] += v0; vq[1] += v1; vq[2] += v2; vq[3] += v3;
      u32 h01 = pk2bf(v0, v1), h23 = pk2bf(v2, v3);
      u32 l01 = pk2bf(v0 - ubf(h01 << 16), v1 - ubf(h01 & 0xffff0000u));
      u32 l23 = pk2bf(v2 - ubf(h23 << 16), v3 - ubf(h23 & 0xffff0000u));
      size_t base = ((size_t)bh * 1024 + n0 + 16 * nf + li) * 64 + 16 * w + g * 4;
      u32x2 ph = {h01, h23}, pl = {l01, l23};
      *(u32x2*)(qh + base) = ph;
      *(u32x2*)(ql + base) = pl;
      int cbo = (16 * nf + li) * 72 + 16 * w + 4 * g;
      *(u32*)&cb_h[cbo] = h01;
      *(u32*)&cb_h[cbo + 2] = h23;
      *(u32*)&cb_l[cbo] = l01;
      *(u32*)&cb_l[cbo + 2] = l23;
    }
#pragma unroll
    for (int r = 0; r < 4; ++r) {  // deterministic qsum partial per (bh, on, d)
      float s = vq[r];
      s += __shfl_xor(s, 1, 64);
      s += __shfl_xor(s, 2, 64);
      s += __shfl_xor(s, 4, 64);
      s += __shfl_xor(s, 8, 64);
      if (li == 0) qpart[((size_t)bh * 16 + on) * 64 + 16 * w + 4 * g + r] = s;
    }
    __syncthreads();
    // Vw tile = W_lin @ s  (split 3-term), wave w -> e rows [16w,16w+16)
    f32x4 acc2[4];
#pragma unroll
    for (int i = 0; i < 4; ++i) acc2[i] = zz;
    u16x8 la_h[2], la_l[2];
#pragma unroll
    for (int ks = 0; ks < 2; ++ks) {
      la_h[ks] = *(const u16x8*)&lw_h[(16 * w + li) * 72 + g * 8 + 32 * ks];
      la_l[ks] = *(const u16x8*)&lw_l[(16 * w + li) * 72 + g * 8 + 32 * ks];
    }
#pragma unroll
    for (int ks = 0; ks < 2; ++ks) {
#pragma unroll
      for (int nf = 0; nf < 4; ++nf) {
        u16x8 qb = *(const u16x8*)&cb_h[(16 * nf + li) * 72 + g * 8 + 32 * ks];
        u16x8 ql2 = *(const u16x8*)&cb_l[(16 * nf + li) * 72 + g * 8 + 32 * ks];
        acc2[nf] = mfma16(la_h[ks], qb, acc2[nf]);
        acc2[nf] = mfma16(la_h[ks], ql2, acc2[nf]);
        acc2[nf] = mfma16(la_l[ks], qb, acc2[nf]);
      }
    }
    __syncthreads();  // all cb reads done; reuse xt_h as bounce
#pragma unroll
    for (int nf = 0; nf < 4; ++nf) {
#pragma unroll
      for (int r = 0; r < 4; ++r)
        xt_h[(16 * w + 4 * g + r) * 72 + 16 * nf + li] = b2u(acc2[nf][r]);
    }
    __syncthreads();
    {  // coalesced Vw store: [bh][e][n]
      int e = t >> 2, nc = (t & 3) * 16;
      u16x8 v0 = *(const u16x8*)&xt_h[e * 72 + nc];
      u16x8 v1 = *(const u16x8*)&xt_h[e * 72 + nc + 8];
      size_t base = ((size_t)bh * 64 + e) * 1024 + n0 + nc;
      *(u16x8*)(vw + base) = v0;
      *(u16x8*)(vw + base + 8) = v1;
    }
  }
}

// ---------------- K2: flash attention per (bh, quarter): 256 j-rows, 2 sets/wave.
// log2-domain energies, ALWAYS-rescale online softmax (R5 control flow), packed converts.
__global__ __launch_bounds__(512, 4) void k_attn(
    const u16* __restrict__ qh, const u16* __restrict__ ql, const u16* __restrict__ vw,
    const float* __restrict__ pos_t, float* __restrict__ pout, float* __restrict__ sump2_g) {
  __shared__ __align__(16) u16 kbuf[2][3][4096];  // [buf][{kh,kl,vw}][64*64] 48KB
  __shared__ __align__(16) u16 ptw_all[8][1024];  // per-wave P scratch 16KB
  __shared__ float wvar[8];
  const int bid = blockIdx.x, bh = bid & 255, quarter = bid >> 8;
  const int b = bh >> 3, h = bh & 7;
  const int t = threadIdx.x, w = t >> 6, lane = t & 63, g = lane >> 4, li = lane & 15;
  char* ptw = (char*)&ptw_all[w][0];
  const u16* qhb = qh + (size_t)bh * 65536;
  const u16* qlb = ql + (size_t)bh * 65536;
  const u16* vwb = vw + (size_t)bh * 65536;
  const float* posb = pos_t + (size_t)h * 65536;
  const float SIL = 0.088388347648318447f * 1.4426950408889634f;  // (1/sqrt(128))*log2e
  const float L2E = 1.4426950408889634f;
  const int swz = (li & 7) << 4;
  f32x4 zz = {0.f, 0.f, 0.f, 0.f};

  // ---- Q fragments for both sets (log2-scaled), straight from global, packed split
  u16x8 qb_h[2][2], qb_l[2][2];
  const int jr0 = quarter * 256 + 16 * w;
#pragma unroll
  for (int s = 0; s < 2; ++s) {
    int jr = jr0 + s * 128 + li;
#pragma unroll
    for (int ks = 0; ks < 2; ++ks) {
      int dc = 32 * ks + 8 * g;
      u16x8 hh = *(const u16x8*)(qhb + (size_t)jr * 64 + dc);
      u16x8 ll = *(const u16x8*)(qlb + (size_t)jr * 64 + dc);
      const float* sp = posb + (size_t)jr * 64 + dc;
      f32x4 p0 = *(const f32x4*)sp, p1 = *(const f32x4*)(sp + 4);
      u32 AW[4], LW[4];
#pragma unroll
      for (int p = 0; p < 4; ++p) {
        float pa = (2 * p < 4) ? p0[2 * p] : p1[2 * p - 4];
        float pb = (2 * p + 1 < 4) ? p0[2 * p + 1] : p1[2 * p - 3];
        float v0 = (bf2f(hh[2 * p]) + bf2f(ll[2 * p])) * SIL + pa * L2E;
        float v1 = (bf2f(hh[2 * p + 1]) + bf2f(ll[2 * p + 1])) * SIL + pb * L2E;
        u32 hw = pk2bf(v0, v1);
        AW[p] = hw;
        LW[p] = pk2bf(v0 - ubf(hw << 16), v1 - ubf(hw & 0xffff0000u));
      }
      u32x4 av = {AW[0], AW[1], AW[2], AW[3]};
      u32x4 lv = {LW[0], LW[1], LW[2], LW[3]};
      qb_h[s][ks] = __builtin_bit_cast(u16x8, av);
      qb_l[s][ks] = __builtin_bit_cast(u16x8, lv);
    }
  }

#define STAGE(bb, k0)                                                         \
  do {                                                                        \
    int r8 = lane >> 3, c8 = (lane & 7) ^ r8;                                 \
    int rq = (k0) + 8 * w + r8;                                               \
    gl16(qhb + (size_t)rq * 64 + 8 * c8, &kbuf[bb][0][w * 512]);              \
    gl16(qlb + (size_t)rq * 64 + 8 * c8, &kbuf[bb][1][w * 512]);              \
    gl16(vwb + (size_t)(8 * w + r8) * 1024 + (k0) + 8 * c8,                   \
         &kbuf[bb][2][w * 512]);                                              \
  } while (0)

  float m0 = -3.0e38f, l0 = 0.f, s20 = 0.f;
  float m1 = -3.0e38f, l1 = 0.f, s21 = 0.f;
  f32x4 O0[4], O1[4];
#pragma unroll
  for (int df = 0; df < 4; ++df) {
    O0[df] = zz;
    O1[df] = zz;
  }

  // ALWAYS-rescale online softmax (exp2 domain); P-pack via packed convert.
#define SOFT(S, mm, ll, ss2, O)                                               \
  do {                                                                        \
    float t0 = fmaxf(fmaxf(S[0][0], S[0][1]), fmaxf(S[0][2], S[0][3]));       \
    float t1 = fmaxf(fmaxf(S[1][0], S[1][1]), fmaxf(S[1][2], S[1][3]));       \
    float t2 = fmaxf(fmaxf(S[2][0], S[2][1]), fmaxf(S[2][2], S[2][3]));       \
    float t3 = fmaxf(fmaxf(S[3][0], S[3][1]), fmaxf(S[3][2], S[3][3]));       \
    float tm = fmaxf(fmaxf(t0, t1), fmaxf(t2, t3));                           \
    tm = fmaxf(tm, __shfl_xor(tm, 16, 64));                                   \
    tm = fmaxf(tm, __shfl_xor(tm, 32, 64));                                   \
    float mn = fmaxf(mm, tm);                                                 \
    float cr = __builtin_amdgcn_exp2f(mm - mn);                               \
    mm = mn;                                                                  \
    float ps = 0.f, p2 = 0.f;                                                 \
    _Pragma("unroll") for (int nf = 0; nf < 4; ++nf) {                        \
      _Pragma("unroll") for (int r = 0; r < 4; ++r) {                         \
        float e = __builtin_amdgcn_exp2f(S[nf][r] - mn);                      \
        S[nf][r] = e;                                                         \
        ps += e;                                                              \
        p2 = fmaf(e, e, p2);                                                  \
      }                                                                       \
    }                                                                         \
    ll = ll * cr + ps;                                                        \
    ss2 = ss2 * cr * cr + p2;                                                 \
    _Pragma("unroll") for (int df = 0; df < 4; ++df) O[df] *= cr;             \
    _Pragma("unroll") for (int nf = 0; nf < 4; ++nf) {                        \
      u32 w0 = pk2bf(S[nf][0], S[nf][1]);                                     \
      u32 w1 = pk2bf(S[nf][2], S[nf][3]);                                     \
      int slot = 2 * nf + (g >> 1);                                           \
      u32x2 pk = {w0, w1};                                                    \
      *(u32x2*)(ptw + li * 128 + ((slot * 16) ^ swz) + (g & 1) * 8) = pk;     \
    }                                                                         \
  } while (0)

  int cur = 0;
  STAGE(0, 0);
  __syncthreads();
  for (int kc = 0; kc < 16; ++kc) {
    if (kc < 15) STAGE(cur ^ 1, (kc + 1) * 64);
    const char* kb = (const char*)&kbuf[cur][0][0];
    const char* lb = (const char*)&kbuf[cur][1][0];
    const char* vb = (const char*)&kbuf[cur][2][0];
    f32x4 S0[4] = {zz, zz, zz, zz};
    f32x4 S1[4] = {zz, zz, zz, zz};
    __builtin_amdgcn_s_setprio(1);
#pragma unroll
    for (int ks = 0; ks < 2; ++ks) {
#pragma unroll
      for (int nf = 0; nf < 4; ++nf) {
        int off = (16 * nf + li) * 128 + (((4 * ks + g) * 16) ^ swz);
        u16x8 kh = *(const u16x8*)(kb + off);
        u16x8 kl = *(const u16x8*)(lb + off);
        S0[nf] = mfma16(kh, qb_h[0][ks], S0[nf]);
        S0[nf] = mfma16(kl, qb_h[0][ks], S0[nf]);
        S0[nf] = mfma16(kh, qb_l[0][ks], S0[nf]);
        S1[nf] = mfma16(kh, qb_h[1][ks], S1[nf]);
        S1[nf] = mfma16(kl, qb_h[1][ks], S1[nf]);
        S1[nf] = mfma16(kh, qb_l[1][ks], S1[nf]);
      }
    }
    __builtin_amdgcn_s_setprio(0);
    SOFT(S0, m0, l0, s20, O0);
    u16x8 pb0[2];
    pb0[0] = *(const u16x8*)(ptw + li * 128 + ((g * 16) ^ swz));
    pb0[1] = *(const u16x8*)(ptw + li * 128 + (((4 + g) * 16) ^ swz));
    SOFT(S1, m1, l1, s21, O1);
    u16x8 pb1[2];
    pb1[0] = *(const u16x8*)(ptw + li * 128 + ((g * 16) ^ swz));
    pb1[1] = *(const u16x8*)(ptw + li * 128 + (((4 + g) * 16) ^ swz));
    __builtin_amdgcn_s_setprio(1);
#pragma unroll
    for (int ks = 0; ks < 2; ++ks) {
#pragma unroll
      for (int df = 0; df < 4; ++df) {
        u16x8 va = *(const u16x8*)(vb + (16 * df + li) * 128 + (((4 * ks + g) * 16) ^ swz));
        O0[df] = mfma16(va, pb0[ks], O0[df]);
        O1[df] = mfma16(va, pb1[ks], O1[df]);
      }
    }
    __builtin_amdgcn_s_setprio(0);
    __syncthreads();
    cur ^= 1;
  }

  // ---- finalize stats (lane-local rows), accumulate sum(P~^2)
  float wacc = 0.f;
  l0 += __shfl_xor(l0, 16, 64);
  l0 += __shfl_xor(l0, 32, 64);
  s20 += __shfl_xor(s20, 16, 64);
  s20 += __shfl_xor(s20, 32, 64);
  l1 += __shfl_xor(l1, 16, 64);
  l1 += __shfl_xor(l1, 32, 64);
  s21 += __shfl_xor(s21, 16, 64);
  s21 += __shfl_xor(s21, 32, 64);
  float il0 = 1.0f / l0, il1 = 1.0f / l1;
#pragma unroll
  for (int df = 0; df < 4; ++df) {
    O0[df] *= il0;
    O1[df] *= il1;
  }
  {
    float s2w = s20 * il0 * il0;
    s2w += __shfl_xor(s2w, 1, 64);
    s2w += __shfl_xor(s2w, 2, 64);
    s2w += __shfl_xor(s2w, 4, 64);
    s2w += __shfl_xor(s2w, 8, 64);
    wacc += s2w;
    float s2w1 = s21 * il1 * il1;
    s2w1 += __shfl_xor(s2w1, 1, 64);
    s2w1 += __shfl_xor(s2w1, 2, 64);
    s2w1 += __shfl_xor(s2w1, 4, 64);
    s2w1 += __shfl_xor(s2w1, 8, 64);
    wacc += s2w1;
  }
  if (lane == 0) wvar[w] = wacc;

  // ---- write both sets via f32 LDS bounce (alias kbuf), coalesced stores
  float* bounce = (float*)&kbuf[0][0][0];  // [64 e][132]
#pragma unroll
  for (int s = 0; s < 2; ++s) {
    const int jg0 = quarter * 256 + s * 128;
    __syncthreads();
#pragma unroll
    for (int df = 0; df < 4; ++df)
#pragma unroll
      for (int r = 0; r < 4; ++r)
        bounce[(df * 16 + g * 4 + r) * 132 + 16 * w + li] = s ? O1[df][r] : O0[df][r];
    __syncthreads();
#pragma unroll
    for (int p = 0; p < 4; ++p) {
      int idx = p * 512 + t;
      int e = idx >> 5, ch = idx & 31;
      f32x4 v = *(const f32x4*)&bounce[e * 132 + ch * 4];
      *(f32x4*)&pout[((size_t)b * 512 + h * 64 + e) * 1024 + jg0 + ch * 4] = v;
    }
  }
  __syncthreads();
  if (t == 0) {
    float s = 0.f;
#pragma unroll
    for (int i = 0; i < 8; ++i) s += wvar[i];
    sump2_g[bid] = s;
  }
#undef STAGE
#undef SOFT
}

// ---------------- K3a: per-bh constants: cvec[e] = blin - isv*mu*(W@qsum), isv
__global__ __launch_bounds__(64) void k_cvec(
    const float* __restrict__ qpart, const float* __restrict__ sump2_g,
    const float* __restrict__ Wlin, const float* __restrict__ blin,
    float* __restrict__ cvec_g, float* __restrict__ isv_g) {
  const int bh = blockIdx.x, t = threadIdx.x;
  __shared__ float qs[64];
  float s = 0.f;
#pragma unroll
  for (int on = 0; on < 16; ++on) s += qpart[(size_t)bh * 1024 + on * 64 + t];
  qs[t] = s;
  __syncthreads();
  const float MU = 1.0f / 1024.0f;
  float sp2 = sump2_g[bh] + sump2_g[bh + 256] + sump2_g[bh + 512] + sump2_g[bh + 768];
  float var = sp2 * (1.0f / 1048576.0f) - MU * MU;
  float isv = 1.0f / sqrtf(var + EPS);
  float wq = 0.f;
  for (int d = 0; d < 64; ++d) wq += Wlin[t * 64 + d] * qs[d];
  cvec_g[bh * 64 + t] = blin[t] - isv * MU * wq;
  if (t == 0) isv_g[bh] = isv;
}

// ---------------- K3b: out = isv * P_out + cvec[e] + x  (in-place, pure stream)
__global__ __launch_bounds__(256) void k_fin(
    float* __restrict__ out, const float* __restrict__ x,
    const float* __restrict__ cvec_g, const float* __restrict__ isv_g) {
  const int bid = blockIdx.x, t = threadIdx.x;
  const int bh = bid >> 3, part = bid & 7;
  const float isv = isv_g[bh];
  const size_t base = (size_t)bh * 65536 + part * 8192;
#pragma unroll
  for (int it = 0; it < 8; ++it) {
    size_t off = base + it * 1024 + t * 4;
    float cv = cvec_g[bh * 64 + part * 8 + it];
    f32x4 po = *(const f32x4*)(out + off);
    f32x4 xv = *(const f32x4*)(x + off);
    f32x4 res;
#pragma unroll
    for (int k = 0; k < 4; ++k) res[k] = isv * po[k] + cv + xv[k];
    *(f32x4*)(out + off) = res;
  }
}

extern "C" void kernel_launch(void* const* d_in, const int* in_sizes, int n_in,
                              void* d_out, int out_size, void* d_ws, size_t ws_size,
                              hipStream_t stream) {
  const float* x = (const float*)d_in[0];
  const float* Ws = (const float*)d_in[1];
  const float* bs = (const float*)d_in[2];
  const float* rh = (const float*)d_in[3];
  const float* rw = (const float*)d_in[4];
  const float* Wl = (const float*)d_in[5];
  const float* bl = (const float*)d_in[6];
  char* wsb = (char*)d_ws;
  u16* qh = (u16*)wsb;                               // 32 MiB  q hi, n-major [bh][n][d]
  u16* ql = (u16*)(wsb + (size_t)33554432);          // 32 MiB  q lo, n-major
  u16* vw = (u16*)(wsb + (size_t)67108864);          // 32 MiB  Vw=W_lin@q hi, d-major [bh][e][n]
  float* pos_t = (float*)(wsb + (size_t)100663296);  //  2 MiB  pos [h][n][d]
  float* qpart = (float*)(wsb + (size_t)102760448);  //  1 MiB  qsum partials [bh][16 on][64 d]
  float* s2g = (float*)(wsb + (size_t)103809024);    //  4 KiB  sum(P~^2) per block (1024)
  float* cvec = (float*)(wsb + (size_t)103813120);   // 64 KiB  cvec [bh][64]
  float* isvg = (float*)(wsb + (size_t)103878656);   //  1 KiB  isv per bh
  float* out = (float*)d_out;

  k_pos<<<2048, 256, 0, stream>>>(rh, rw, pos_t);
  k_conv<<<dim3(16, 32), 256, 0, stream>>>(x, Ws, bs, Wl, qh, ql, vw, qpart);
  k_attn<<<1024, 512, 0, stream>>>(qh, ql, vw, pos_t, out, s2g);
  k_cvec<<<256, 64, 0, stream>>>(qpart, s2g, Wl, bl, cvec, isvg);
  k_fin<<<2048, 256, 0, stream>>>(out, x, cvec, isvg);
}

// Round 8
// 334.397 us; speedup vs baseline: 2.7306x; 1.0855x over previous
//
#include <hip/hip_runtime.h>

#define EPS 1e-5f

typedef unsigned short u16;
typedef unsigned int u32;
typedef __attribute__((ext_vector_type(8))) u16 u16x8;
typedef __attribute__((ext_vector_type(4))) u16 u16x4;
typedef __attribute__((ext_vector_type(2))) u32 u32x2;
typedef __attribute__((ext_vector_type(4))) u32 u32x4;
typedef __attribute__((ext_vector_type(8))) __bf16 bf16x8;
typedef __attribute__((ext_vector_type(2))) __bf16 bf16x2;
typedef __attribute__((ext_vector_type(4))) float f32x4;
typedef __attribute__((ext_vector_type(2))) float f32x2;

typedef __attribute__((address_space(3))) u32 lds_u32;
typedef __attribute__((address_space(1))) const u32 gbl_u32;

__device__ __forceinline__ float bf2f(u16 h) {
  return __uint_as_float(((unsigned)h) << 16);
}
__device__ __forceinline__ u32 pk2bf(float a, float b) {  // elt0 -> low 16 bits, RNE
  f32x2 v = {a, b};
  return __builtin_bit_cast(u32, __builtin_convertvector(v, bf16x2));
}
__device__ __forceinline__ u16 b2u(float f) {
  return __builtin_bit_cast(u16, (__bf16)f);
}
__device__ __forceinline__ float ubf(u32 u) { return __uint_as_float(u); }
__device__ __forceinline__ f32x4 mfma16(u16x8 a, u16x8 b, f32x4 c) {
  return __builtin_amdgcn_mfma_f32_16x16x32_bf16(
      __builtin_bit_cast(bf16x8, a), __builtin_bit_cast(bf16x8, b), c, 0, 0, 0);
}
__device__ __forceinline__ void gl16(const u16* g, u16* l) {
  __builtin_amdgcn_global_load_lds((gbl_u32*)g, (lds_u32*)l, 16, 0, 0);
}

// ---------------- K0: pos[h][n][d] = rel_h[h,d,hh] + rel_w[h,d,ww], n = ww*32+hh
__global__ void k_pos(const float* __restrict__ rel_h, const float* __restrict__ rel_w,
                      float* __restrict__ pos_t) {
  int t = blockIdx.x * 256 + threadIdx.x;  // 524288 exact
  int d = t & 63;
  int n = (t >> 6) & 1023;
  int h = t >> 16;
  int hh = n & 31, ww = n >> 5;
  pos_t[t] = rel_h[(h * 64 + d) * 32 + hh] + rel_w[(h * 64 + d) * 32 + ww];
}

// ---------------- K_wsplit: W_start (512x512 f32) -> bf16 hi/lo, row-major
__global__ __launch_bounds__(256) void k_wsplit(const float* __restrict__ Ws,
                                                u16* __restrict__ wsh, u16* __restrict__ wsl) {
  int i = (blockIdx.x * 256 + threadIdx.x) * 4;  // 256 blocks covers 512*512
  f32x4 v = *(const f32x4*)(Ws + i);
  u32 h01 = pk2bf(v[0], v[1]), h23 = pk2bf(v[2], v[3]);
  u32 l01 = pk2bf(v[0] - ubf(h01 << 16), v[1] - ubf(h01 & 0xffff0000u));
  u32 l23 = pk2bf(v[2] - ubf(h23 << 16), v[3] - ubf(h23 & 0xffff0000u));
  u32x2 hh = {h01, h23}, ll = {l01, l23};
  *(u32x2*)(wsh + i) = hh;
  *(u32x2*)(wsl + i) = ll;
}

// ---------------- K1: s = W_start @ x + b -> qh/ql (n-major) + qsum partials.
// kc-outer: x staged once per kc; W tiles via gl16, wave-local rows, dbuf + vmcnt(4).
__global__ __launch_bounds__(256, 2) void k_conv(
    const float* __restrict__ x, const u16* __restrict__ wsh, const u16* __restrict__ wsl,
    const float* __restrict__ bs,
    u16* __restrict__ qh, u16* __restrict__ ql, float* __restrict__ qpart) {
  __shared__ u16 xt_h[64 * 72], xt_l[64 * 72];
  __shared__ __align__(16) u16 wbuf[2][2][4096];  // [buf][h/l][64*64]
  const int on = blockIdx.x, b = blockIdx.y, n0 = on * 64;
  const int t = threadIdx.x, w = t >> 6, lane = t & 63, g = lane >> 4, li = lane & 15;
  const int r8 = lane >> 3, c8 = (lane & 7) ^ r8;
  f32x4 zz = {0.f, 0.f, 0.f, 0.f};
  f32x4 acc[8][4];
#pragma unroll
  for (int ob = 0; ob < 8; ++ob)
#pragma unroll
    for (int i = 0; i < 4; ++i) acc[ob][i] = zz;

  for (int kc = 0; kc < 8; ++kc) {
    const int c0 = kc * 64;
    __syncthreads();  // xt/wbuf reads of previous kc complete
    {  // prefetch W tile ob=0 (wave w stages exactly its own rows 16w..16w+16)
#pragma unroll
      for (int p = 0; p < 2; ++p) {
        int rq = 16 * w + 8 * p + r8;
        gl16(wsh + (size_t)rq * 512 + c0 + 8 * c8, &wbuf[0][0][(16 * w + 8 * p) * 64]);
        gl16(wsl + (size_t)rq * 512 + c0 + 8 * c8, &wbuf[0][1][(16 * w + 8 * p) * 64]);
      }
    }
    {  // stage x tile transposed -> xt[n][c] (R7 path)
      int c = t >> 2, ns = (t & 3) * 16;
      const float* src = x + ((size_t)b * 512 + c0 + c) * 1024 + n0 + ns;
#pragma unroll
      for (int k = 0; k < 4; ++k) {
        f32x4 f = *(const f32x4*)(src + 4 * k);
#pragma unroll
        for (int j = 0; j < 4; ++j) {
          float v = f[j];
          u16 hv = b2u(v);
          int n = ns + 4 * k + j;
          xt_h[n * 72 + c] = hv;
          xt_l[n * 72 + c] = b2u(v - bf2f(hv));
        }
      }
    }
    __syncthreads();  // xt visible; wbuf[0] drained by barrier's vmcnt(0)
    u16x8 bx_h[2][4], bx_l[2][4];
#pragma unroll
    for (int ks = 0; ks < 2; ++ks)
#pragma unroll
      for (int nf = 0; nf < 4; ++nf) {
        bx_h[ks][nf] = *(const u16x8*)&xt_h[(16 * nf + li) * 72 + g * 8 + 32 * ks];
        bx_l[ks][nf] = *(const u16x8*)&xt_l[(16 * nf + li) * 72 + g * 8 + 32 * ks];
      }
#pragma unroll
    for (int ob = 0; ob < 8; ++ob) {
      if (ob < 7) {
#pragma unroll
        for (int p = 0; p < 2; ++p) {
          int rq = (ob + 1) * 64 + 16 * w + 8 * p + r8;
          gl16(wsh + (size_t)rq * 512 + c0 + 8 * c8,
               &wbuf[(ob + 1) & 1][0][(16 * w + 8 * p) * 64]);
          gl16(wsl + (size_t)rq * 512 + c0 + 8 * c8,
               &wbuf[(ob + 1) & 1][1][(16 * w + 8 * p) * 64]);
        }
        asm volatile("s_waitcnt vmcnt(4)" ::: "memory");
      } else {
        asm volatile("s_waitcnt vmcnt(0)" ::: "memory");
      }
      const char* wb = (const char*)&wbuf[ob & 1][0][0];
      const char* wl = (const char*)&wbuf[ob & 1][1][0];
      u16x8 ah[2], al[2];
#pragma unroll
      for (int ks = 0; ks < 2; ++ks) {
        int off = (16 * w + li) * 128 + (((4 * ks + g) * 16) ^ ((li & 7) << 4));
        ah[ks] = *(const u16x8*)(wb + off);
        al[ks] = *(const u16x8*)(wl + off);
      }
#pragma unroll
      for (int ks = 0; ks < 2; ++ks)
#pragma unroll
        for (int nf = 0; nf < 4; ++nf) {
          acc[ob][nf] = mfma16(ah[ks], bx_h[ks][nf], acc[ob][nf]);
          acc[ob][nf] = mfma16(ah[ks], bx_l[ks][nf], acc[ob][nf]);
          acc[ob][nf] = mfma16(al[ks], bx_h[ks][nf], acc[ob][nf]);
        }
    }
  }
  // ---- epilogue: bias, qh/ql stores (bitwise R7), qsum partials
#pragma unroll
  for (int ob = 0; ob < 8; ++ob) {
    const int o0 = ob * 64, bh = b * 8 + ob;
    float bias[4];
#pragma unroll
    for (int r = 0; r < 4; ++r) bias[r] = bs[o0 + 16 * w + g * 4 + r];
    float vq[4] = {0.f, 0.f, 0.f, 0.f};
#pragma unroll
    for (int nf = 0; nf < 4; ++nf) {
      float v0 = acc[ob][nf][0] + bias[0], v1 = acc[ob][nf][1] + bias[1];
      float v2 = acc[ob][nf][2] + bias[2], v3 = acc[ob][nf][3] + bias[3];
      vq[0] += v0; vq[1] += v1; vq[2] += v2; vq[3] += v3;
      u32 h01 = pk2bf(v0, v1), h23 = pk2bf(v2, v3);
      u32 l01 = pk2bf(v0 - ubf(h01 << 16), v1 - ubf(h01 & 0xffff0000u));
      u32 l23 = pk2bf(v2 - ubf(h23 << 16), v3 - ubf(h23 & 0xffff0000u));
      size_t base = ((size_t)bh * 1024 + n0 + 16 * nf + li) * 64 + 16 * w + g * 4;
      u32x2 ph = {h01, h23}, pl = {l01, l23};
      *(u32x2*)(qh + base) = ph;
      *(u32x2*)(ql + base) = pl;
    }
#pragma unroll
    for (int r = 0; r < 4; ++r) {
      float s = vq[r];
      s += __shfl_xor(s, 1, 64);
      s += __shfl_xor(s, 2, 64);
      s += __shfl_xor(s, 4, 64);
      s += __shfl_xor(s, 8, 64);
      if (li == 0) qpart[((size_t)bh * 16 + on) * 64 + 16 * w + 4 * g + r] = s;
    }
  }
}

// ---------------- K_vw: Vw = W_lin @ s per bh (3-term split, bitwise == R7's Vw)
__global__ __launch_bounds__(256) void k_vw(
    const u16* __restrict__ qh, const u16* __restrict__ ql,
    const float* __restrict__ Wlin, u16* __restrict__ vw) {
  __shared__ __align__(16) u16 qbuf[2][2][4096];  // [buf][h/l][64n x 64d]
  __shared__ u16 lw_h[64 * 72], lw_l[64 * 72];
  __shared__ u16 bounce[64 * 72];
  const int bh = blockIdx.x;
  const int t = threadIdx.x, w = t >> 6, lane = t & 63, g = lane >> 4, li = lane & 15;
  const int r8 = lane >> 3, c8 = (lane & 7) ^ r8;
  const u16* qhb = qh + (size_t)bh * 65536;
  const u16* qlb = ql + (size_t)bh * 65536;
  f32x4 zz = {0.f, 0.f, 0.f, 0.f};

  {  // stage W_lin split
    int e = t >> 2, ds = (t & 3) * 16;
    const float* src = Wlin + e * 64 + ds;
    float arr[16];
#pragma unroll
    for (int k = 0; k < 4; ++k) *(f32x4*)&arr[4 * k] = *(const f32x4*)(src + 4 * k);
#pragma unroll
    for (int p = 0; p < 8; ++p) {
      float a = arr[2 * p], c = arr[2 * p + 1];
      u32 hw = pk2bf(a, c);
      u32 lw = pk2bf(a - ubf(hw << 16), c - ubf(hw & 0xffff0000u));
      *(u32*)&lw_h[e * 72 + ds + 2 * p] = hw;
      *(u32*)&lw_l[e * 72 + ds + 2 * p] = lw;
    }
  }
#define STAGE_Q(bb, n0_)                                                      \
  do {                                                                        \
    _Pragma("unroll") for (int p = 0; p < 2; ++p) {                           \
      int rq = (n0_) + 8 * (w + 4 * p) + r8;                                  \
      gl16(qhb + (size_t)rq * 64 + 8 * c8, &qbuf[bb][0][(8 * (w + 4 * p)) * 64]); \
      gl16(qlb + (size_t)rq * 64 + 8 * c8, &qbuf[bb][1][(8 * (w + 4 * p)) * 64]); \
    }                                                                         \
  } while (0)

  STAGE_Q(0, 0);
  __syncthreads();  // lw visible + tile 0 drained
  u16x8 la_h[2], la_l[2];
#pragma unroll
  for (int ks = 0; ks < 2; ++ks) {
    la_h[ks] = *(const u16x8*)&lw_h[(16 * w + li) * 72 + g * 8 + 32 * ks];
    la_l[ks] = *(const u16x8*)&lw_l[(16 * w + li) * 72 + g * 8 + 32 * ks];
  }
  int cur = 0;
  for (int nt = 0; nt < 16; ++nt) {
    if (nt < 15) STAGE_Q(cur ^ 1, (nt + 1) * 64);
    f32x4 acc2[4] = {zz, zz, zz, zz};
    const char* qb0 = (const char*)&qbuf[cur][0][0];
    const char* qb1 = (const char*)&qbuf[cur][1][0];
#pragma unroll
    for (int ks = 0; ks < 2; ++ks)
#pragma unroll
      for (int nf = 0; nf < 4; ++nf) {
        int off = (16 * nf + li) * 128 + (((4 * ks + g) * 16) ^ ((li & 7) << 4));
        u16x8 qv = *(const u16x8*)(qb0 + off);
        u16x8 lv = *(const u16x8*)(qb1 + off);
        acc2[nf] = mfma16(la_h[ks], qv, acc2[nf]);
        acc2[nf] = mfma16(la_h[ks], lv, acc2[nf]);
        acc2[nf] = mfma16(la_l[ks], qv, acc2[nf]);
      }
    __syncthreads();  // tile reads done; next-tile gl16 drained; bounce free
#pragma unroll
    for (int nf = 0; nf < 4; ++nf)
#pragma unroll
      for (int r = 0; r < 4; ++r)
        bounce[(16 * w + 4 * g + r) * 72 + 16 * nf + li] = b2u(acc2[nf][r]);
    __syncthreads();
    {  // coalesced Vw store: [bh][e][n]
      int e = t >> 2, nc = (t & 3) * 16;
      u16x8 v0 = *(const u16x8*)&bounce[e * 72 + nc];
      u16x8 v1 = *(const u16x8*)&bounce[e * 72 + nc + 8];
      size_t base = ((size_t)bh * 64 + e) * 1024 + nt * 64 + nc;
      *(u16x8*)(vw + base) = v0;
      *(u16x8*)(vw + base + 8) = v1;
    }
    cur ^= 1;
  }
#undef STAGE_Q
}

// ---------------- K2: flash attention (R7 verbatim)
__global__ __launch_bounds__(512, 4) void k_attn(
    const u16* __restrict__ qh, const u16* __restrict__ ql, const u16* __restrict__ vw,
    const float* __restrict__ pos_t, float* __restrict__ pout, float* __restrict__ sump2_g) {
  __shared__ __align__(16) u16 kbuf[2][3][4096];
  __shared__ __align__(16) u16 ptw_all[8][1024];
  __shared__ float wvar[8];
  const int bid = blockIdx.x, bh = bid & 255, quarter = bid >> 8;
  const int b = bh >> 3, h = bh & 7;
  const int t = threadIdx.x, w = t >> 6, lane = t & 63, g = lane >> 4, li = lane & 15;
  char* ptw = (char*)&ptw_all[w][0];
  const u16* qhb = qh + (size_t)bh * 65536;
  const u16* qlb = ql + (size_t)bh * 65536;
  const u16* vwb = vw + (size_t)bh * 65536;
  const float* posb = pos_t + (size_t)h * 65536;
  const float SIL = 0.088388347648318447f * 1.4426950408889634f;
  const float L2E = 1.4426950408889634f;
  const int swz = (li & 7) << 4;
  f32x4 zz = {0.f, 0.f, 0.f, 0.f};

  u16x8 qb_h[2][2], qb_l[2][2];
  const int jr0 = quarter * 256 + 16 * w;
#pragma unroll
  for (int s = 0; s < 2; ++s) {
    int jr = jr0 + s * 128 + li;
#pragma unroll
    for (int ks = 0; ks < 2; ++ks) {
      int dc = 32 * ks + 8 * g;
      u16x8 hh = *(const u16x8*)(qhb + (size_t)jr * 64 + dc);
      u16x8 ll = *(const u16x8*)(qlb + (size_t)jr * 64 + dc);
      const float* sp = posb + (size_t)jr * 64 + dc;
      f32x4 p0 = *(const f32x4*)sp, p1 = *(const f32x4*)(sp + 4);
      u32 AW[4], LW[4];
#pragma unroll
      for (int p = 0; p < 4; ++p) {
        float pa = (2 * p < 4) ? p0[2 * p] : p1[2 * p - 4];
        float pb = (2 * p + 1 < 4) ? p0[2 * p + 1] : p1[2 * p - 3];
        float v0 = (bf2f(hh[2 * p]) + bf2f(ll[2 * p])) * SIL + pa * L2E;
        float v1 = (bf2f(hh[2 * p + 1]) + bf2f(ll[2 * p + 1])) * SIL + pb * L2E;
        u32 hw = pk2bf(v0, v1);
        AW[p] = hw;
        LW[p] = pk2bf(v0 - ubf(hw << 16), v1 - ubf(hw & 0xffff0000u));
      }
      u32x4 av = {AW[0], AW[1], AW[2], AW[3]};
      u32x4 lv = {LW[0], LW[1], LW[2], LW[3]};
      qb_h[s][ks] = __builtin_bit_cast(u16x8, av);
      qb_l[s][ks] = __builtin_bit_cast(u16x8, lv);
    }
  }

#define STAGE(bb, k0)                                                         \
  do {                                                                        \
    int r8 = lane >> 3, c8 = (lane & 7) ^ r8;                                 \
    int rq = (k0) + 8 * w + r8;                                               \
    gl16(qhb + (size_t)rq * 64 + 8 * c8, &kbuf[bb][0][w * 512]);              \
    gl16(qlb + (size_t)rq * 64 + 8 * c8, &kbuf[bb][1][w * 512]);              \
    gl16(vwb + (size_t)(8 * w + r8) * 1024 + (k0) + 8 * c8,                   \
         &kbuf[bb][2][w * 512]);                                              \
  } while (0)

  float m0 = -3.0e38f, l0 = 0.f, s20 = 0.f;
  float m1 = -3.0e38f, l1 = 0.f, s21 = 0.f;
  f32x4 O0[4], O1[4];
#pragma unroll
  for (int df = 0; df < 4; ++df) {
    O0[df] = zz;
    O1[df] = zz;
  }

#define SOFT(S, mm, ll, ss2, O)                                               \
  do {                                                                        \
    float t0 = fmaxf(fmaxf(S[0][0], S[0][1]), fmaxf(S[0][2], S[0][3]));       \
    float t1 = fmaxf(fmaxf(S[1][0], S[1][1]), fmaxf(S[1][2], S[1][3]));       \
    float t2 = fmaxf(fmaxf(S[2][0], S[2][1]), fmaxf(S[2][2], S[2][3]));       \
    float t3 = fmaxf(fmaxf(S[3][0], S[3][1]), fmaxf(S[3][2], S[3][3]));       \
    float tm = fmaxf(fmaxf(t0, t1), fmaxf(t2, t3));                           \
    tm = fmaxf(tm, __shfl_xor(tm, 16, 64));                                   \
    tm = fmaxf(tm, __shfl_xor(tm, 32, 64));                                   \
    float mn = fmaxf(mm, tm);                                                 \
    float cr = __builtin_amdgcn_exp2f(mm - mn);                               \
    mm = mn;                                                                  \
    float ps = 0.f, p2 = 0.f;                                                 \
    _Pragma("unroll") for (int nf = 0; nf < 4; ++nf) {                        \
      _Pragma("unroll") for (int r = 0; r < 4; ++r) {                         \
        float e = __builtin_amdgcn_exp2f(S[nf][r] - mn);                      \
        S[nf][r] = e;                                                         \
        ps += e;                                                              \
        p2 = fmaf(e, e, p2);                                                  \
      }                                                                       \
    }                                                                         \
    ll = ll * cr + ps;                                                        \
    ss2 = ss2 * cr * cr + p2;                                                 \
    _Pragma("unroll") for (int df = 0; df < 4; ++df) O[df] *= cr;             \
    _Pragma("unroll") for (int nf = 0; nf < 4; ++nf) {                        \
      u32 w0 = pk2bf(S[nf][0], S[nf][1]);                                     \
      u32 w1 = pk2bf(S[nf][2], S[nf][3]);                                     \
      int slot = 2 * nf + (g >> 1);                                           \
      u32x2 pk = {w0, w1};                                                    \
      *(u32x2*)(ptw + li * 128 + ((slot * 16) ^ swz) + (g & 1) * 8) = pk;     \
    }                                                                         \
  } while (0)

  int cur = 0;
  STAGE(0, 0);
  __syncthreads();
  for (int kc = 0; kc < 16; ++kc) {
    if (kc < 15) STAGE(cur ^ 1, (kc + 1) * 64);
    const char* kb = (const char*)&kbuf[cur][0][0];
    const char* lb = (const char*)&kbuf[cur][1][0];
    const char* vb = (const char*)&kbuf[cur][2][0];
    f32x4 S0[4] = {zz, zz, zz, zz};
    f32x4 S1[4] = {zz, zz, zz, zz};
    __builtin_amdgcn_s_setprio(1);
#pragma unroll
    for (int ks = 0; ks < 2; ++ks) {
#pragma unroll
      for (int nf = 0; nf < 4; ++nf) {
        int off = (16 * nf + li) * 128 + (((4 * ks + g) * 16) ^ swz);
        u16x8 kh = *(const u16x8*)(kb + off);
        u16x8 kl = *(const u16x8*)(lb + off);
        S0[nf] = mfma16(kh, qb_h[0][ks], S0[nf]);
        S0[nf] = mfma16(kl, qb_h[0][ks], S0[nf]);
        S0[nf] = mfma16(kh, qb_l[0][ks], S0[nf]);
        S1[nf] = mfma16(kh, qb_h[1][ks], S1[nf]);
        S1[nf] = mfma16(kl, qb_h[1][ks], S1[nf]);
        S1[nf] = mfma16(kh, qb_l[1][ks], S1[nf]);
      }
    }
    __builtin_amdgcn_s_setprio(0);
    SOFT(S0, m0, l0, s20, O0);
    u16x8 pb0[2];
    pb0[0] = *(const u16x8*)(ptw + li * 128 + ((g * 16) ^ swz));
    pb0[1] = *(const u16x8*)(ptw + li * 128 + (((4 + g) * 16) ^ swz));
    SOFT(S1, m1, l1, s21, O1);
    u16x8 pb1[2];
    pb1[0] = *(const u16x8*)(ptw + li * 128 + ((g * 16) ^ swz));
    pb1[1] = *(const u16x8*)(ptw + li * 128 + (((4 + g) * 16) ^ swz));
    __builtin_amdgcn_s_setprio(1);
#pragma unroll
    for (int ks = 0; ks < 2; ++ks) {
#pragma unroll
      for (int df = 0; df < 4; ++df) {
        u16x8 va = *(const u16x8*)(vb + (16 * df + li) * 128 + (((4 * ks + g) * 16) ^ swz));
        O0[df] = mfma16(va, pb0[ks], O0[df]);
        O1[df] = mfma16(va, pb1[ks], O1[df]);
      }
    }
    __builtin_amdgcn_s_setprio(0);
    __syncthreads();
    cur ^= 1;
  }

  float wacc = 0.f;
  l0 += __shfl_xor(l0, 16, 64);
  l0 += __shfl_xor(l0, 32, 64);
  s20 += __shfl_xor(s20, 16, 64);
  s20 += __shfl_xor(s20, 32, 64);
  l1 += __shfl_xor(l1, 16, 64);
  l1 += __shfl_xor(l1, 32, 64);
  s21 += __shfl_xor(s21, 16, 64);
  s21 += __shfl_xor(s21, 32, 64);
  float il0 = 1.0f / l0, il1 = 1.0f / l1;
#pragma unroll
  for (int df = 0; df < 4; ++df) {
    O0[df] *= il0;
    O1[df] *= il1;
  }
  {
    float s2w = s20 * il0 * il0;
    s2w += __shfl_xor(s2w, 1, 64);
    s2w += __shfl_xor(s2w, 2, 64);
    s2w += __shfl_xor(s2w, 4, 64);
    s2w += __shfl_xor(s2w, 8, 64);
    wacc += s2w;
    float s2w1 = s21 * il1 * il1;
    s2w1 += __shfl_xor(s2w1, 1, 64);
    s2w1 += __shfl_xor(s2w1, 2, 64);
    s2w1 += __shfl_xor(s2w1, 4, 64);
    s2w1 += __shfl_xor(s2w1, 8, 64);
    wacc += s2w1;
  }
  if (lane == 0) wvar[w] = wacc;

  float* bounce = (float*)&kbuf[0][0][0];
#pragma unroll
  for (int s = 0; s < 2; ++s) {
    const int jg0 = quarter * 256 + s * 128;
    __syncthreads();
#pragma unroll
    for (int df = 0; df < 4; ++df)
#pragma unroll
      for (int r = 0; r < 4; ++r)
        bounce[(df * 16 + g * 4 + r) * 132 + 16 * w + li] = s ? O1[df][r] : O0[df][r];
    __syncthreads();
#pragma unroll
    for (int p = 0; p < 4; ++p) {
      int idx = p * 512 + t;
      int e = idx >> 5, ch = idx & 31;
      f32x4 v = *(const f32x4*)&bounce[e * 132 + ch * 4];
      *(f32x4*)&pout[((size_t)b * 512 + h * 64 + e) * 1024 + jg0 + ch * 4] = v;
    }
  }
  __syncthreads();
  if (t == 0) {
    float s = 0.f;
#pragma unroll
    for (int i = 0; i < 8; ++i) s += wvar[i];
    sump2_g[bid] = s;
  }
#undef STAGE
#undef SOFT
}

// ---------------- K3a: per-bh constants
__global__ __launch_bounds__(64) void k_cvec(
    const float* __restrict__ qpart, const float* __restrict__ sump2_g,
    const float* __restrict__ Wlin, const float* __restrict__ blin,
    float* __restrict__ cvec_g, float* __restrict__ isv_g) {
  const int bh = blockIdx.x, t = threadIdx.x;
  __shared__ float qs[64];
  float s = 0.f;
#pragma unroll
  for (int on = 0; on < 16; ++on) s += qpart[(size_t)bh * 1024 + on * 64 + t];
  qs[t] = s;
  __syncthreads();
  const float MU = 1.0f / 1024.0f;
  float sp2 = sump2_g[bh] + sump2_g[bh + 256] + sump2_g[bh + 512] + sump2_g[bh + 768];
  float var = sp2 * (1.0f / 1048576.0f) - MU * MU;
  float isv = 1.0f / sqrtf(var + EPS);
  float wq = 0.f;
  for (int d = 0; d < 64; ++d) wq += Wlin[t * 64 + d] * qs[d];
  cvec_g[bh * 64 + t] = blin[t] - isv * MU * wq;
  if (t == 0) isv_g[bh] = isv;
}

// ---------------- K3b: out = isv * P_out + cvec[e] + x
__global__ __launch_bounds__(256) void k_fin(
    float* __restrict__ out, const float* __restrict__ x,
    const float* __restrict__ cvec_g, const float* __restrict__ isv_g) {
  const int bid = blockIdx.x, t = threadIdx.x;
  const int bh = bid >> 3, part = bid & 7;
  const float isv = isv_g[bh];
  const size_t base = (size_t)bh * 65536 + part * 8192;
#pragma unroll
  for (int it = 0; it < 8; ++it) {
    size_t off = base + it * 1024 + t * 4;
    float cv = cvec_g[bh * 64 + part * 8 + it];
    f32x4 po = *(const f32x4*)(out + off);
    f32x4 xv = *(const f32x4*)(x + off);
    f32x4 res;
#pragma unroll
    for (int k = 0; k < 4; ++k) res[k] = isv * po[k] + cv + xv[k];
    *(f32x4*)(out + off) = res;
  }
}

extern "C" void kernel_launch(void* const* d_in, const int* in_sizes, int n_in,
                              void* d_out, int out_size, void* d_ws, size_t ws_size,
                              hipStream_t stream) {
  const float* x = (const float*)d_in[0];
  const float* Ws = (const float*)d_in[1];
  const float* bs = (const float*)d_in[2];
  const float* rh = (const float*)d_in[3];
  const float* rw = (const float*)d_in[4];
  const float* Wl = (const float*)d_in[5];
  const float* bl = (const float*)d_in[6];
  char* wsb = (char*)d_ws;
  u16* qh = (u16*)wsb;                               // 32 MiB  q hi, n-major [bh][n][d]
  u16* ql = (u16*)(wsb + (size_t)33554432);          // 32 MiB  q lo, n-major
  u16* vw = (u16*)(wsb + (size_t)67108864);          // 32 MiB  Vw hi, d-major [bh][e][n]
  float* pos_t = (float*)(wsb + (size_t)100663296);  //  2 MiB  pos [h][n][d]
  float* qpart = (float*)(wsb + (size_t)102760448);  //  1 MiB  qsum partials
  float* s2g = (float*)(wsb + (size_t)103809024);    //  4 KiB
  float* cvec = (float*)(wsb + (size_t)103813120);   // 64 KiB
  float* isvg = (float*)(wsb + (size_t)103878656);   //  1 KiB
  u16* wsh = (u16*)(wsb + (size_t)103880704);        // 512 KiB W_start hi
  u16* wsl = (u16*)(wsb + (size_t)104404992);        // 512 KiB W_start lo
  float* out = (float*)d_out;

  k_wsplit<<<256, 256, 0, stream>>>(Ws, wsh, wsl);
  k_pos<<<2048, 256, 0, stream>>>(rh, rw, pos_t);
  k_conv<<<dim3(16, 32), 256, 0, stream>>>(x, wsh, wsl, bs, qh, ql, qpart);
  k_vw<<<256, 256, 0, stream>>>(qh, ql, Wl, vw);
  k_attn<<<1024, 512, 0, stream>>>(qh, ql, vw, pos_t, out, s2g);
  k_cvec<<<256, 64, 0, stream>>>(qpart, s2g, Wl, bl, cvec, isvg);
  k_fin<<<2048, 256, 0, stream>>>(out, x, cvec, isvg);
}

// Round 9
// 320.092 us; speedup vs baseline: 2.8527x; 1.0447x over previous
//
#include <hip/hip_runtime.h>

#define EPS 1e-5f

typedef unsigned short u16;
typedef unsigned int u32;
typedef __attribute__((ext_vector_type(8))) u16 u16x8;
typedef __attribute__((ext_vector_type(4))) u16 u16x4;
typedef __attribute__((ext_vector_type(2))) u32 u32x2;
typedef __attribute__((ext_vector_type(4))) u32 u32x4;
typedef __attribute__((ext_vector_type(8))) __bf16 bf16x8;
typedef __attribute__((ext_vector_type(2))) __bf16 bf16x2;
typedef __attribute__((ext_vector_type(4))) float f32x4;
typedef __attribute__((ext_vector_type(2))) float f32x2;

typedef __attribute__((address_space(3))) u32 lds_u32;
typedef __attribute__((address_space(1))) const u32 gbl_u32;

__device__ __forceinline__ float bf2f(u16 h) {
  return __uint_as_float(((unsigned)h) << 16);
}
__device__ __forceinline__ u32 pk2bf(float a, float b) {  // elt0 -> low 16 bits, RNE
  f32x2 v = {a, b};
  return __builtin_bit_cast(u32, __builtin_convertvector(v, bf16x2));
}
__device__ __forceinline__ u16 b2u(float f) {
  return __builtin_bit_cast(u16, (__bf16)f);
}
__device__ __forceinline__ float ubf(u32 u) { return __uint_as_float(u); }
__device__ __forceinline__ f32x4 mfma16(u16x8 a, u16x8 b, f32x4 c) {
  return __builtin_amdgcn_mfma_f32_16x16x32_bf16(
      __builtin_bit_cast(bf16x8, a), __builtin_bit_cast(bf16x8, b), c, 0, 0, 0);
}
__device__ __forceinline__ void gl16(const u16* g, u16* l) {
  __builtin_amdgcn_global_load_lds((gbl_u32*)g, (lds_u32*)l, 16, 0, 0);
}

// ---------------- K_init: fused W_start split (blocks 0..255) + pos table (256..2303)
__global__ __launch_bounds__(256) void k_init(
    const float* __restrict__ Ws, u16* __restrict__ wsh, u16* __restrict__ wsl,
    const float* __restrict__ rel_h, const float* __restrict__ rel_w,
    float* __restrict__ pos_t) {
  int bid = blockIdx.x;
  if (bid < 256) {
    int i = (bid * 256 + threadIdx.x) * 4;
    f32x4 v = *(const f32x4*)(Ws + i);
    u32 h01 = pk2bf(v[0], v[1]), h23 = pk2bf(v[2], v[3]);
    u32 l01 = pk2bf(v[0] - ubf(h01 << 16), v[1] - ubf(h01 & 0xffff0000u));
    u32 l23 = pk2bf(v[2] - ubf(h23 << 16), v[3] - ubf(h23 & 0xffff0000u));
    u32x2 hh = {h01, h23}, ll = {l01, l23};
    *(u32x2*)(wsh + i) = hh;
    *(u32x2*)(wsl + i) = ll;
  } else {
    int t = (bid - 256) * 256 + threadIdx.x;  // 524288 exact
    int d = t & 63;
    int n = (t >> 6) & 1023;
    int h = t >> 16;
    int hh = n & 31, ww = n >> 5;
    pos_t[t] = rel_h[(h * 64 + d) * 32 + hh] + rel_w[(h * 64 + d) * 32 + ww];
  }
}

// ---------------- K1: s = W_start @ x + b -> qh/ql (n-major) + qsum partials.
// kc-outer; W tiles via gl16 with 3-deep pipeline (vmcnt(8) steady-state).
__global__ __launch_bounds__(256, 2) void k_conv(
    const float* __restrict__ x, const u16* __restrict__ wsh, const u16* __restrict__ wsl,
    const float* __restrict__ bs,
    u16* __restrict__ qh, u16* __restrict__ ql, float* __restrict__ qpart) {
  __shared__ u16 xt_h[64 * 72], xt_l[64 * 72];
  __shared__ __align__(16) u16 wbuf[3][2][4096];  // [buf][h/l][64*64]  48KB
  const int on = blockIdx.x, b = blockIdx.y, n0 = on * 64;
  const int t = threadIdx.x, w = t >> 6, lane = t & 63, g = lane >> 4, li = lane & 15;
  const int r8 = lane >> 3, c8 = (lane & 7) ^ r8;
  f32x4 zz = {0.f, 0.f, 0.f, 0.f};
  f32x4 acc[8][4];
#pragma unroll
  for (int ob = 0; ob < 8; ++ob)
#pragma unroll
    for (int i = 0; i < 4; ++i) acc[ob][i] = zz;

#define WSTAGE(buf, ob_, c0_)                                                 \
  do {                                                                        \
    _Pragma("unroll") for (int p = 0; p < 2; ++p) {                           \
      int rq = (ob_) * 64 + 16 * w + 8 * p + r8;                              \
      gl16(wsh + (size_t)rq * 512 + (c0_) + 8 * c8,                           \
           &wbuf[buf][0][(16 * w + 8 * p) * 64]);                             \
      gl16(wsl + (size_t)rq * 512 + (c0_) + 8 * c8,                           \
           &wbuf[buf][1][(16 * w + 8 * p) * 64]);                             \
    }                                                                         \
  } while (0)

  for (int kc = 0; kc < 8; ++kc) {
    const int c0 = kc * 64;
    __syncthreads();  // prev kc's xt/wbuf reads complete
    // x loads first (oldest in vmcnt FIFO -> converts don't wait on W stages)
    int c = t >> 2, ns = (t & 3) * 16;
    const float* src = x + ((size_t)b * 512 + c0 + c) * 1024 + n0 + ns;
    f32x4 xr[4];
#pragma unroll
    for (int k = 0; k < 4; ++k) xr[k] = *(const f32x4*)(src + 4 * k);
    // W prefetch ob0, ob1
    WSTAGE(0, 0, c0);
    WSTAGE(1, 1, c0);
    // convert + ds_write xt
#pragma unroll
    for (int k = 0; k < 4; ++k)
#pragma unroll
      for (int j = 0; j < 4; ++j) {
        float v = xr[k][j];
        u16 hv = b2u(v);
        int n = ns + 4 * k + j;
        xt_h[n * 72 + c] = hv;
        xt_l[n * 72 + c] = b2u(v - bf2f(hv));
      }
    __syncthreads();  // xt visible; ob0/ob1 + x drained by barrier
    u16x8 bx_h[2][4], bx_l[2][4];
#pragma unroll
    for (int ks = 0; ks < 2; ++ks)
#pragma unroll
      for (int nf = 0; nf < 4; ++nf) {
        bx_h[ks][nf] = *(const u16x8*)&xt_h[(16 * nf + li) * 72 + g * 8 + 32 * ks];
        bx_l[ks][nf] = *(const u16x8*)&xt_l[(16 * nf + li) * 72 + g * 8 + 32 * ks];
      }
#pragma unroll
    for (int ob = 0; ob < 8; ++ob) {
      if (ob < 6) WSTAGE((ob + 2) % 3, ob + 2, c0);
      if (ob >= 2 && ob < 6) {
        asm volatile("s_waitcnt vmcnt(8)" ::: "memory");
      } else if (ob == 6) {
        asm volatile("s_waitcnt vmcnt(4)" ::: "memory");
      } else if (ob == 7) {
        asm volatile("s_waitcnt vmcnt(0)" ::: "memory");
      }
      const char* wb = (const char*)&wbuf[ob % 3][0][0];
      const char* wl = (const char*)&wbuf[ob % 3][1][0];
      u16x8 ah[2], al[2];
#pragma unroll
      for (int ks = 0; ks < 2; ++ks) {
        int off = (16 * w + li) * 128 + (((4 * ks + g) * 16) ^ ((li & 7) << 4));
        ah[ks] = *(const u16x8*)(wb + off);
        al[ks] = *(const u16x8*)(wl + off);
      }
#pragma unroll
      for (int ks = 0; ks < 2; ++ks)
#pragma unroll
        for (int nf = 0; nf < 4; ++nf) {
          acc[ob][nf] = mfma16(ah[ks], bx_h[ks][nf], acc[ob][nf]);
          acc[ob][nf] = mfma16(ah[ks], bx_l[ks][nf], acc[ob][nf]);
          acc[ob][nf] = mfma16(al[ks], bx_h[ks][nf], acc[ob][nf]);
        }
    }
  }
#undef WSTAGE
  // ---- epilogue: bias, qh/ql stores (bitwise R8), qsum partials
#pragma unroll
  for (int ob = 0; ob < 8; ++ob) {
    const int o0 = ob * 64, bh = b * 8 + ob;
    float bias[4];
#pragma unroll
    for (int r = 0; r < 4; ++r) bias[r] = bs[o0 + 16 * w + g * 4 + r];
    float vq[4] = {0.f, 0.f, 0.f, 0.f};
#pragma unroll
    for (int nf = 0; nf < 4; ++nf) {
      float v0 = acc[ob][nf][0] + bias[0], v1 = acc[ob][nf][1] + bias[1];
      float v2 = acc[ob][nf][2] + bias[2], v3 = acc[ob][nf][3] + bias[3];
      vq[0] += v0; vq[1] += v1; vq[2] += v2; vq[3] += v3;
      u32 h01 = pk2bf(v0, v1), h23 = pk2bf(v2, v3);
      u32 l01 = pk2bf(v0 - ubf(h01 << 16), v1 - ubf(h01 & 0xffff0000u));
      u32 l23 = pk2bf(v2 - ubf(h23 << 16), v3 - ubf(h23 & 0xffff0000u));
      size_t base = ((size_t)bh * 1024 + n0 + 16 * nf + li) * 64 + 16 * w + g * 4;
      u32x2 ph = {h01, h23}, pl = {l01, l23};
      *(u32x2*)(qh + base) = ph;
      *(u32x2*)(ql + base) = pl;
    }
#pragma unroll
    for (int r = 0; r < 4; ++r) {
      float s = vq[r];
      s += __shfl_xor(s, 1, 64);
      s += __shfl_xor(s, 2, 64);
      s += __shfl_xor(s, 4, 64);
      s += __shfl_xor(s, 8, 64);
      if (li == 0) qpart[((size_t)bh * 16 + on) * 64 + 16 * w + 4 * g + r] = s;
    }
  }
}

// ---------------- K_vw: Vw = W_lin @ s per (bh, n-half). grid 512, 2 blocks/CU.
__global__ __launch_bounds__(256) void k_vw(
    const u16* __restrict__ qh, const u16* __restrict__ ql,
    const float* __restrict__ Wlin, u16* __restrict__ vw) {
  __shared__ __align__(16) u16 qbuf[2][2][4096];  // [buf][h/l][64n x 64d]
  __shared__ u16 lw_h[64 * 72], lw_l[64 * 72];
  __shared__ u16 bounce[64 * 72];
  const int bh = blockIdx.x >> 1, half = blockIdx.x & 1;
  const int t = threadIdx.x, w = t >> 6, lane = t & 63, g = lane >> 4, li = lane & 15;
  const int r8 = lane >> 3, c8 = (lane & 7) ^ r8;
  const u16* qhb = qh + (size_t)bh * 65536;
  const u16* qlb = ql + (size_t)bh * 65536;
  f32x4 zz = {0.f, 0.f, 0.f, 0.f};

  {  // stage W_lin split
    int e = t >> 2, ds = (t & 3) * 16;
    const float* src = Wlin + e * 64 + ds;
    float arr[16];
#pragma unroll
    for (int k = 0; k < 4; ++k) *(f32x4*)&arr[4 * k] = *(const f32x4*)(src + 4 * k);
#pragma unroll
    for (int p = 0; p < 8; ++p) {
      float a = arr[2 * p], c = arr[2 * p + 1];
      u32 hw = pk2bf(a, c);
      u32 lw = pk2bf(a - ubf(hw << 16), c - ubf(hw & 0xffff0000u));
      *(u32*)&lw_h[e * 72 + ds + 2 * p] = hw;
      *(u32*)&lw_l[e * 72 + ds + 2 * p] = lw;
    }
  }
#define STAGE_Q(bb, n0_)                                                      \
  do {                                                                        \
    _Pragma("unroll") for (int p = 0; p < 2; ++p) {                           \
      int rq = (n0_) + 8 * (w + 4 * p) + r8;                                  \
      gl16(qhb + (size_t)rq * 64 + 8 * c8, &qbuf[bb][0][(8 * (w + 4 * p)) * 64]); \
      gl16(qlb + (size_t)rq * 64 + 8 * c8, &qbuf[bb][1][(8 * (w + 4 * p)) * 64]); \
    }                                                                         \
  } while (0)

  const int nt0 = half * 8;
  STAGE_Q(0, nt0 * 64);
  __syncthreads();  // lw visible + tile 0 drained
  u16x8 la_h[2], la_l[2];
#pragma unroll
  for (int ks = 0; ks < 2; ++ks) {
    la_h[ks] = *(const u16x8*)&lw_h[(16 * w + li) * 72 + g * 8 + 32 * ks];
    la_l[ks] = *(const u16x8*)&lw_l[(16 * w + li) * 72 + g * 8 + 32 * ks];
  }
  int cur = 0;
  for (int it = 0; it < 8; ++it) {
    const int nt = nt0 + it;
    if (it < 7) STAGE_Q(cur ^ 1, (nt + 1) * 64);
    f32x4 acc2[4] = {zz, zz, zz, zz};
    const char* qb0 = (const char*)&qbuf[cur][0][0];
    const char* qb1 = (const char*)&qbuf[cur][1][0];
#pragma unroll
    for (int ks = 0; ks < 2; ++ks)
#pragma unroll
      for (int nf = 0; nf < 4; ++nf) {
        int off = (16 * nf + li) * 128 + (((4 * ks + g) * 16) ^ ((li & 7) << 4));
        u16x8 qv = *(const u16x8*)(qb0 + off);
        u16x8 lv = *(const u16x8*)(qb1 + off);
        acc2[nf] = mfma16(la_h[ks], qv, acc2[nf]);
        acc2[nf] = mfma16(la_h[ks], lv, acc2[nf]);
        acc2[nf] = mfma16(la_l[ks], qv, acc2[nf]);
      }
    __syncthreads();
#pragma unroll
    for (int nf = 0; nf < 4; ++nf)
#pragma unroll
      for (int r = 0; r < 4; ++r)
        bounce[(16 * w + 4 * g + r) * 72 + 16 * nf + li] = b2u(acc2[nf][r]);
    __syncthreads();
    {  // coalesced Vw store: [bh][e][n]
      int e = t >> 2, nc = (t & 3) * 16;
      u16x8 v0 = *(const u16x8*)&bounce[e * 72 + nc];
      u16x8 v1 = *(const u16x8*)&bounce[e * 72 + nc + 8];
      size_t base = ((size_t)bh * 64 + e) * 1024 + nt * 64 + nc;
      *(u16x8*)(vw + base) = v0;
      *(u16x8*)(vw + base + 8) = v1;
    }
    cur ^= 1;
  }
#undef STAGE_Q
}

// ---------------- K2: flash attention (R8 base + deferred rescale THR=12)
__global__ __launch_bounds__(512, 4) void k_attn(
    const u16* __restrict__ qh, const u16* __restrict__ ql, const u16* __restrict__ vw,
    const float* __restrict__ pos_t, float* __restrict__ pout, float* __restrict__ sump2_g) {
  __shared__ __align__(16) u16 kbuf[2][3][4096];
  __shared__ __align__(16) u16 ptw_all[8][1024];
  __shared__ float wvar[8];
  const int bid = blockIdx.x, bh = bid & 255, quarter = bid >> 8;
  const int b = bh >> 3, h = bh & 7;
  const int t = threadIdx.x, w = t >> 6, lane = t & 63, g = lane >> 4, li = lane & 15;
  char* ptw = (char*)&ptw_all[w][0];
  const u16* qhb = qh + (size_t)bh * 65536;
  const u16* qlb = ql + (size_t)bh * 65536;
  const u16* vwb = vw + (size_t)bh * 65536;
  const float* posb = pos_t + (size_t)h * 65536;
  const float SIL = 0.088388347648318447f * 1.4426950408889634f;
  const float L2E = 1.4426950408889634f;
  const int swz = (li & 7) << 4;
  f32x4 zz = {0.f, 0.f, 0.f, 0.f};

  u16x8 qb_h[2][2], qb_l[2][2];
  const int jr0 = quarter * 256 + 16 * w;
#pragma unroll
  for (int s = 0; s < 2; ++s) {
    int jr = jr0 + s * 128 + li;
#pragma unroll
    for (int ks = 0; ks < 2; ++ks) {
      int dc = 32 * ks + 8 * g;
      u16x8 hh = *(const u16x8*)(qhb + (size_t)jr * 64 + dc);
      u16x8 ll = *(const u16x8*)(qlb + (size_t)jr * 64 + dc);
      const float* sp = posb + (size_t)jr * 64 + dc;
      f32x4 p0 = *(const f32x4*)sp, p1 = *(const f32x4*)(sp + 4);
      u32 AW[4], LW[4];
#pragma unroll
      for (int p = 0; p < 4; ++p) {
        float pa = (2 * p < 4) ? p0[2 * p] : p1[2 * p - 4];
        float pb = (2 * p + 1 < 4) ? p0[2 * p + 1] : p1[2 * p - 3];
        float v0 = (bf2f(hh[2 * p]) + bf2f(ll[2 * p])) * SIL + pa * L2E;
        float v1 = (bf2f(hh[2 * p + 1]) + bf2f(ll[2 * p + 1])) * SIL + pb * L2E;
        u32 hw = pk2bf(v0, v1);
        AW[p] = hw;
        LW[p] = pk2bf(v0 - ubf(hw << 16), v1 - ubf(hw & 0xffff0000u));
      }
      u32x4 av = {AW[0], AW[1], AW[2], AW[3]};
      u32x4 lv = {LW[0], LW[1], LW[2], LW[3]};
      qb_h[s][ks] = __builtin_bit_cast(u16x8, av);
      qb_l[s][ks] = __builtin_bit_cast(u16x8, lv);
    }
  }

#define STAGE(bb, k0)                                                         \
  do {                                                                        \
    int r8 = lane >> 3, c8 = (lane & 7) ^ r8;                                 \
    int rq = (k0) + 8 * w + r8;                                               \
    gl16(qhb + (size_t)rq * 64 + 8 * c8, &kbuf[bb][0][w * 512]);              \
    gl16(qlb + (size_t)rq * 64 + 8 * c8, &kbuf[bb][1][w * 512]);              \
    gl16(vwb + (size_t)(8 * w + r8) * 1024 + (k0) + 8 * c8,                   \
         &kbuf[bb][2][w * 512]);                                              \
  } while (0)

  float m0 = -3.0e38f, l0 = 0.f, s20 = 0.f;
  float m1 = -3.0e38f, l1 = 0.f, s21 = 0.f;
  f32x4 O0[4], O1[4];
#pragma unroll
  for (int df = 0; df < 4; ++df) {
    O0[df] = zz;
    O1[df] = zz;
  }

  // Deferred-rescale online softmax (exp2 domain): rescale only when the
  // running max grows by >12 log2-units (P bounded by 2^12; l,s2,O safe in f32).
#define SOFT(S, mm, ll, ss2, O)                                               \
  do {                                                                        \
    float t0 = fmaxf(fmaxf(S[0][0], S[0][1]), fmaxf(S[0][2], S[0][3]));       \
    float t1 = fmaxf(fmaxf(S[1][0], S[1][1]), fmaxf(S[1][2], S[1][3]));       \
    float t2 = fmaxf(fmaxf(S[2][0], S[2][1]), fmaxf(S[2][2], S[2][3]));       \
    float t3 = fmaxf(fmaxf(S[3][0], S[3][1]), fmaxf(S[3][2], S[3][3]));       \
    float tm = fmaxf(fmaxf(t0, t1), fmaxf(t2, t3));                           \
    tm = fmaxf(tm, __shfl_xor(tm, 16, 64));                                   \
    tm = fmaxf(tm, __shfl_xor(tm, 32, 64));                                   \
    if (__any(tm > mm + 12.f)) {                                              \
      float mn = fmaxf(mm, tm);                                               \
      float cr = __builtin_amdgcn_exp2f(mm - mn);                             \
      mm = mn;                                                                \
      ll *= cr;                                                               \
      ss2 *= cr * cr;                                                         \
      _Pragma("unroll") for (int df = 0; df < 4; ++df) O[df] *= cr;           \
    }                                                                         \
    float ps = 0.f, p2 = 0.f;                                                 \
    _Pragma("unroll") for (int nf = 0; nf < 4; ++nf) {                        \
      _Pragma("unroll") for (int r = 0; r < 4; ++r) {                         \
        float e = __builtin_amdgcn_exp2f(S[nf][r] - mm);                      \
        S[nf][r] = e;                                                         \
        ps += e;                                                              \
        p2 = fmaf(e, e, p2);                                                  \
      }                                                                       \
    }                                                                         \
    ll += ps;                                                                 \
    ss2 += p2;                                                                \
    _Pragma("unroll") for (int nf = 0; nf < 4; ++nf) {                        \
      u32 w0 = pk2bf(S[nf][0], S[nf][1]);                                     \
      u32 w1 = pk2bf(S[nf][2], S[nf][3]);                                     \
      int slot = 2 * nf + (g >> 1);                                           \
      u32x2 pk = {w0, w1};                                                    \
      *(u32x2*)(ptw + li * 128 + ((slot * 16) ^ swz) + (g & 1) * 8) = pk;     \
    }                                                                         \
  } while (0)

  int cur = 0;
  STAGE(0, 0);
  __syncthreads();
  for (int kc = 0; kc < 16; ++kc) {
    if (kc < 15) STAGE(cur ^ 1, (kc + 1) * 64);
    const char* kb = (const char*)&kbuf[cur][0][0];
    const char* lb = (const char*)&kbuf[cur][1][0];
    const char* vb = (const char*)&kbuf[cur][2][0];
    f32x4 S0[4] = {zz, zz, zz, zz};
    f32x4 S1[4] = {zz, zz, zz, zz};
    __builtin_amdgcn_s_setprio(1);
#pragma unroll
    for (int ks = 0; ks < 2; ++ks) {
#pragma unroll
      for (int nf = 0; nf < 4; ++nf) {
        int off = (16 * nf + li) * 128 + (((4 * ks + g) * 16) ^ swz);
        u16x8 kh = *(const u16x8*)(kb + off);
        u16x8 kl = *(const u16x8*)(lb + off);
        S0[nf] = mfma16(kh, qb_h[0][ks], S0[nf]);
        S0[nf] = mfma16(kl, qb_h[0][ks], S0[nf]);
        S0[nf] = mfma16(kh, qb_l[0][ks], S0[nf]);
        S1[nf] = mfma16(kh, qb_h[1][ks], S1[nf]);
        S1[nf] = mfma16(kl, qb_h[1][ks], S1[nf]);
        S1[nf] = mfma16(kh, qb_l[1][ks], S1[nf]);
      }
    }
    __builtin_amdgcn_s_setprio(0);
    SOFT(S0, m0, l0, s20, O0);
    u16x8 pb0[2];
    pb0[0] = *(const u16x8*)(ptw + li * 128 + ((g * 16) ^ swz));
    pb0[1] = *(const u16x8*)(ptw + li * 128 + (((4 + g) * 16) ^ swz));
    SOFT(S1, m1, l1, s21, O1);
    u16x8 pb1[2];
    pb1[0] = *(const u16x8*)(ptw + li * 128 + ((g * 16) ^ swz));
    pb1[1] = *(const u16x8*)(ptw + li * 128 + (((4 + g) * 16) ^ swz));
    __builtin_amdgcn_s_setprio(1);
#pragma unroll
    for (int ks = 0; ks < 2; ++ks) {
#pragma unroll
      for (int df = 0; df < 4; ++df) {
        u16x8 va = *(const u16x8*)(vb + (16 * df + li) * 128 + (((4 * ks + g) * 16) ^ swz));
        O0[df] = mfma16(va, pb0[ks], O0[df]);
        O1[df] = mfma16(va, pb1[ks], O1[df]);
      }
    }
    __builtin_amdgcn_s_setprio(0);
    __syncthreads();
    cur ^= 1;
  }

  float wacc = 0.f;
  l0 += __shfl_xor(l0, 16, 64);
  l0 += __shfl_xor(l0, 32, 64);
  s20 += __shfl_xor(s20, 16, 64);
  s20 += __shfl_xor(s20, 32, 64);
  l1 += __shfl_xor(l1, 16, 64);
  l1 += __shfl_xor(l1, 32, 64);
  s21 += __shfl_xor(s21, 16, 64);
  s21 += __shfl_xor(s21, 32, 64);
  float il0 = 1.0f / l0, il1 = 1.0f / l1;
#pragma unroll
  for (int df = 0; df < 4; ++df) {
    O0[df] *= il0;
    O1[df] *= il1;
  }
  {
    float s2w = s20 * il0 * il0;
    s2w += __shfl_xor(s2w, 1, 64);
    s2w += __shfl_xor(s2w, 2, 64);
    s2w += __shfl_xor(s2w, 4, 64);
    s2w += __shfl_xor(s2w, 8, 64);
    wacc += s2w;
    float s2w1 = s21 * il1 * il1;
    s2w1 += __shfl_xor(s2w1, 1, 64);
    s2w1 += __shfl_xor(s2w1, 2, 64);
    s2w1 += __shfl_xor(s2w1, 4, 64);
    s2w1 += __shfl_xor(s2w1, 8, 64);
    wacc += s2w1;
  }
  if (lane == 0) wvar[w] = wacc;

  float* bounce = (float*)&kbuf[0][0][0];
#pragma unroll
  for (int s = 0; s < 2; ++s) {
    const int jg0 = quarter * 256 + s * 128;
    __syncthreads();
#pragma unroll
    for (int df = 0; df < 4; ++df)
#pragma unroll
      for (int r = 0; r < 4; ++r)
        bounce[(df * 16 + g * 4 + r) * 132 + 16 * w + li] = s ? O1[df][r] : O0[df][r];
    __syncthreads();
#pragma unroll
    for (int p = 0; p < 4; ++p) {
      int idx = p * 512 + t;
      int e = idx >> 5, ch = idx & 31;
      f32x4 v = *(const f32x4*)&bounce[e * 132 + ch * 4];
      *(f32x4*)&pout[((size_t)b * 512 + h * 64 + e) * 1024 + jg0 + ch * 4] = v;
    }
  }
  __syncthreads();
  if (t == 0) {
    float s = 0.f;
#pragma unroll
    for (int i = 0; i < 8; ++i) s += wvar[i];
    sump2_g[bid] = s;
  }
#undef STAGE
#undef SOFT
}

// ---------------- K3a: per-bh constants
__global__ __launch_bounds__(64) void k_cvec(
    const float* __restrict__ qpart, const float* __restrict__ sump2_g,
    const float* __restrict__ Wlin, const float* __restrict__ blin,
    float* __restrict__ cvec_g, float* __restrict__ isv_g) {
  const int bh = blockIdx.x, t = threadIdx.x;
  __shared__ float qs[64];
  float s = 0.f;
#pragma unroll
  for (int on = 0; on < 16; ++on) s += qpart[(size_t)bh * 1024 + on * 64 + t];
  qs[t] = s;
  __syncthreads();
  const float MU = 1.0f / 1024.0f;
  float sp2 = sump2_g[bh] + sump2_g[bh + 256] + sump2_g[bh + 512] + sump2_g[bh + 768];
  float var = sp2 * (1.0f / 1048576.0f) - MU * MU;
  float isv = 1.0f / sqrtf(var + EPS);
  float wq = 0.f;
  for (int d = 0; d < 64; ++d) wq += Wlin[t * 64 + d] * qs[d];
  cvec_g[bh * 64 + t] = blin[t] - isv * MU * wq;
  if (t == 0) isv_g[bh] = isv;
}

// ---------------- K3b: out = isv * P_out + cvec[e] + x
__global__ __launch_bounds__(256) void k_fin(
    float* __restrict__ out, const float* __restrict__ x,
    const float* __restrict__ cvec_g, const float* __restrict__ isv_g) {
  const int bid = blockIdx.x, t = threadIdx.x;
  const int bh = bid >> 3, part = bid & 7;
  const float isv = isv_g[bh];
  const size_t base = (size_t)bh * 65536 + part * 8192;
#pragma unroll
  for (int it = 0; it < 8; ++it) {
    size_t off = base + it * 1024 + t * 4;
    float cv = cvec_g[bh * 64 + part * 8 + it];
    f32x4 po = *(const f32x4*)(out + off);
    f32x4 xv = *(const f32x4*)(x + off);
    f32x4 res;
#pragma unroll
    for (int k = 0; k < 4; ++k) res[k] = isv * po[k] + cv + xv[k];
    *(f32x4*)(out + off) = res;
  }
}

extern "C" void kernel_launch(void* const* d_in, const int* in_sizes, int n_in,
                              void* d_out, int out_size, void* d_ws, size_t ws_size,
                              hipStream_t stream) {
  const float* x = (const float*)d_in[0];
  const float* Ws = (const float*)d_in[1];
  const float* bs = (const float*)d_in[2];
  const float* rh = (const float*)d_in[3];
  const float* rw = (const float*)d_in[4];
  const float* Wl = (const float*)d_in[5];
  const float* bl = (const float*)d_in[6];
  char* wsb = (char*)d_ws;
  u16* qh = (u16*)wsb;                               // 32 MiB  q hi, n-major [bh][n][d]
  u16* ql = (u16*)(wsb + (size_t)33554432);          // 32 MiB  q lo, n-major
  u16* vw = (u16*)(wsb + (size_t)67108864);          // 32 MiB  Vw hi, d-major [bh][e][n]
  float* pos_t = (float*)(wsb + (size_t)100663296);  //  2 MiB  pos [h][n][d]
  float* qpart = (float*)(wsb + (size_t)102760448);  //  1 MiB  qsum partials
  float* s2g = (float*)(wsb + (size_t)103809024);    //  4 KiB
  float* cvec = (float*)(wsb + (size_t)103813120);   // 64 KiB
  float* isvg = (float*)(wsb + (size_t)103878656);   //  1 KiB
  u16* wsh = (u16*)(wsb + (size_t)103880704);        // 512 KiB W_start hi
  u16* wsl = (u16*)(wsb + (size_t)104404992);        // 512 KiB W_start lo
  float* out = (float*)d_out;

  k_init<<<2304, 256, 0, stream>>>(Ws, wsh, wsl, rh, rw, pos_t);
  k_conv<<<dim3(16, 32), 256, 0, stream>>>(x, wsh, wsl, bs, qh, ql, qpart);
  k_vw<<<512, 256, 0, stream>>>(qh, ql, Wl, vw);
  k_attn<<<1024, 512, 0, stream>>>(qh, ql, vw, pos_t, out, s2g);
  k_cvec<<<256, 64, 0, stream>>>(qpart, s2g, Wl, bl, cvec, isvg);
  k_fin<<<2048, 256, 0, stream>>>(out, x, cvec, isvg);
}